// Round 4
// baseline (2695.508 us; speedup 1.0000x reference)
//
#include <hip/hip_runtime.h>
#include <math.h>

#define N_NODES 50000
#define N_EDGES 800000
#define D 128
#define T_TYPES 8

typedef short short8 __attribute__((ext_vector_type(8)));
typedef float float4v __attribute__((ext_vector_type(4)));

static __device__ __forceinline__ unsigned short f2bf(float f) {
    unsigned u = __float_as_uint(f);
    u += 0x7fff + ((u >> 16) & 1);   // round-to-nearest-even
    return (unsigned short)(u >> 16);
}
static __device__ __forceinline__ float bf2f(unsigned short b) {
    return __uint_as_float((unsigned)b << 16);
}
// exact two-term split: x ~= hi + lo, error <= 2^-18 |x|
static __device__ __forceinline__ void splitbf(float x, short& hi, short& lo) {
    unsigned short h_ = f2bf(x);
    hi = (short)h_;
    lo = (short)f2bf(x - bf2f(h_));   // x - bf2f(h_) is exact in fp32
}
// 8 contiguous fp32 -> (hi, lo) short8 fragments
static __device__ __forceinline__ void split8(const float* __restrict__ p,
                                              short8& hi, short8& lo) {
    float4 u = *(const float4*)p;
    float4 v = *(const float4*)(p + 4);
    float xs[8] = {u.x, u.y, u.z, u.w, v.x, v.y, v.z, v.w};
#pragma unroll
    for (int j = 0; j < 8; ++j) {
        short a, b;
        splitbf(xs[j], a, b);
        hi[j] = a;
        lo[j] = b;
    }
}

// ---------------------------------------------------------------------------
__global__ void embed_gather(const int* __restrict__ x, const float* __restrict__ emb,
                             float* __restrict__ h) {
    int n = blockIdx.x;
    int d = threadIdx.x;
    h[(size_t)n * D + d] = emb[(size_t)x[n] * D + d];
}

// WrelT[t][f][d] = Wrel[t][d][f], split hi/lo bf16
__global__ void convert_wrelT(const float* __restrict__ Wrel,
                              unsigned short* __restrict__ hi, unsigned short* __restrict__ lo) {
    int idx = blockIdx.x * 256 + threadIdx.x; // 0..131071
    int t = idx >> 14;
    int rem = idx & 16383;
    int f = rem >> 7;
    int d = rem & 127;
    short a, b;
    splitbf(Wrel[((size_t)t << 14) + (d << 7) + f], a, b);
    hi[idx] = (unsigned short)a;
    lo[idx] = (unsigned short)b;
}

// GRU weights keep [3D][D] layout (already B^T form), split hi/lo
__global__ void convert_w(const float* __restrict__ in,
                          unsigned short* __restrict__ hi, unsigned short* __restrict__ lo, int n) {
    int idx = blockIdx.x * 256 + threadIdx.x;
    if (idx < n) {
        short a, b;
        splitbf(in[idx], a, b);
        hi[idx] = (unsigned short)a;
        lo[idx] = (unsigned short)b;
    }
}

// ---------------------------------------------------------------------------
// CSR build over dst
__global__ void count_deg(const int* __restrict__ ei, int* __restrict__ deg) {
    int e = blockIdx.x * 256 + threadIdx.x;
    if (e >= N_EDGES) return;
    atomicAdd(&deg[ei[N_EDGES + e]], 1);
}

// One block, 1024 threads. cursor may alias deg (read-before-write per index).
__global__ __launch_bounds__(1024) void scan_deg(const int* __restrict__ deg,
                                                 int* __restrict__ rs,
                                                 int* __restrict__ cursor) {
    __shared__ int sums[1024];
    const int tid = threadIdx.x;
    const int CH = 49;
    const int base = tid * CH;
    int s = 0;
    for (int i = 0; i < CH; ++i) {
        int idx = base + i;
        if (idx < N_NODES) s += deg[idx];
    }
    sums[tid] = s;
    __syncthreads();
    for (int ofs = 1; ofs < 1024; ofs <<= 1) {
        int v = (tid >= ofs) ? sums[tid - ofs] : 0;
        __syncthreads();
        sums[tid] += v;
        __syncthreads();
    }
    int run = sums[tid] - s;
    for (int i = 0; i < CH; ++i) {
        int idx = base + i;
        if (idx < N_NODES) {
            int dv = deg[idx];      // read BEFORE cursor write (cursor aliases deg)
            rs[idx] = run;
            cursor[idx] = run;
            run += dv;
        }
    }
    if (tid == 0) rs[N_NODES] = N_EDGES;
}

__global__ void fill_csr(const int* __restrict__ ei, const int* __restrict__ et,
                         int* __restrict__ cursor, int* __restrict__ packed) {
    int e = blockIdx.x * 256 + threadIdx.x;
    if (e >= N_EDGES) return;
    int dst = ei[N_EDGES + e];
    int pos = atomicAdd(&cursor[dst], 1);
    packed[pos] = (ei[e] << 3) | et[e];
}

// ---------------------------------------------------------------------------
// Relational transform, bf16x3 MFMA: Ht[n, y*128+f] = sum_d h[n,d]*Wrel[tbase+y][d][f]
// Block 256 thr = 4 waves; wave covers 16 rows x 128 cols of one type.
__global__ __launch_bounds__(256) void gemm_rel(const float* __restrict__ h,
                                                const unsigned short* __restrict__ Whi,
                                                const unsigned short* __restrict__ Wlo,
                                                float* __restrict__ Ht,
                                                int tbase, int ncols) {
    const int tid = threadIdx.x;
    const int wave = tid >> 6, lane = tid & 63;
    const int q = lane >> 4, li = lane & 15;
    const int m_base = blockIdx.x * 64 + wave * 16;
    const int t = tbase + blockIdx.y;

    int arow = m_base + li;
    if (arow > N_NODES - 1) arow = N_NODES - 1;
    const float* Ap = h + (size_t)arow * D + q * 8;
    const size_t boff = ((size_t)t << 14) + (size_t)li * D + q * 8;
    const unsigned short* Bh = Whi + boff;
    const unsigned short* Bl = Wlo + boff;

    float4v acc[8];
#pragma unroll
    for (int ft = 0; ft < 8; ++ft) acc[ft] = (float4v){0.f, 0.f, 0.f, 0.f};

#pragma unroll
    for (int ks = 0; ks < 4; ++ks) {
        short8 ahi, alo;
        split8(Ap + ks * 32, ahi, alo);
#pragma unroll
        for (int ft = 0; ft < 8; ++ft) {
            short8 bh = *(const short8*)(Bh + ft * 2048 + ks * 32);
            short8 bl = *(const short8*)(Bl + ft * 2048 + ks * 32);
            acc[ft] = __builtin_amdgcn_mfma_f32_16x16x32_bf16(ahi, bh, acc[ft], 0, 0, 0);
            acc[ft] = __builtin_amdgcn_mfma_f32_16x16x32_bf16(alo, bh, acc[ft], 0, 0, 0);
            acc[ft] = __builtin_amdgcn_mfma_f32_16x16x32_bf16(ahi, bl, acc[ft], 0, 0, 0);
        }
    }

    const int orow0 = m_base + q * 4;
    const int colbase = (blockIdx.y << 7) + li;   // LOCAL type index in Ht
#pragma unroll
    for (int ft = 0; ft < 8; ++ft) {
        int col = colbase + ft * 16;
#pragma unroll
        for (int r = 0; r < 4; ++r) {
            int orow = orow0 + r;
            if (orow < N_NODES) Ht[(size_t)orow * ncols + col] = acc[ft][r];
        }
    }
}

// ---------------------------------------------------------------------------
// CSR aggregation: one wave per dst node, fp32 in/out.
// FULL: all 8 types resident (ncols=1024). else: types [tbase,tbase+4), ncols=512.
// INIT: start from b_node; else accumulate onto existing aggr.
template <bool FULL, bool INIT>
__global__ __launch_bounds__(256) void aggregate_csr(const int* __restrict__ rs,
                                                     const int* __restrict__ packed,
                                                     const float* __restrict__ Ht,
                                                     const int* __restrict__ nt,
                                                     const float* __restrict__ b_node,
                                                     float* __restrict__ aggr,
                                                     int tbase, int ncols) {
    int n = blockIdx.x * 4 + (threadIdx.x >> 6);
    if (n >= N_NODES) return;
    const int lane = threadIdx.x & 63;
    const int beg = rs[n], end = rs[n + 1];

    float2 acc;
    if (INIT) {
        acc = ((const float2*)(b_node + (size_t)nt[n] * D))[lane];
    } else {
        acc = ((const float2*)(aggr + (size_t)n * D))[lane];
    }

    if (FULL) {
        int i = beg;
        for (; i + 1 < end; i += 2) {
            int pk0 = packed[i];
            int pk1 = packed[i + 1];
            float2 v0 = ((const float2*)(Ht + ((size_t)(pk0 >> 3) << 10) + ((pk0 & 7) << 7)))[lane];
            float2 v1 = ((const float2*)(Ht + ((size_t)(pk1 >> 3) << 10) + ((pk1 & 7) << 7)))[lane];
            acc.x += v0.x + v1.x;
            acc.y += v0.y + v1.y;
        }
        if (i < end) {
            int pk = packed[i];
            float2 v = ((const float2*)(Ht + ((size_t)(pk >> 3) << 10) + ((pk & 7) << 7)))[lane];
            acc.x += v.x;
            acc.y += v.y;
        }
    } else {
        for (int i = beg; i < end; ++i) {
            int pk = packed[i];
            int rel = (pk & 7) - tbase;
            if ((unsigned)rel < 4u) {
                float2 v = ((const float2*)(Ht + (size_t)(pk >> 3) * ncols + (rel << 7)))[lane];
                acc.x += v.x;
                acc.y += v.y;
            }
        }
    }
    ((float2*)(aggr + (size_t)n * D))[lane] = acc;
}

// ---------------------------------------------------------------------------
// Fused GRU, bf16x3 MFMA. Block = 512 thr = 8 waves; block owns 16 rows x 128 cols.
// All reads precede __syncthreads(); h writes after (rows block-exclusive).
__global__ __launch_bounds__(512) void gru_mfma(const float* __restrict__ aggr,
                                                const unsigned short* __restrict__ Wihi,
                                                const unsigned short* __restrict__ Wilo,
                                                const unsigned short* __restrict__ Whhi,
                                                const unsigned short* __restrict__ Whlo,
                                                const float* __restrict__ b_ih,
                                                const float* __restrict__ b_hh,
                                                float* __restrict__ h) {
    const int tid = threadIdx.x;
    const int wave = tid >> 6, lane = tid & 63;
    const int q = lane >> 4, li = lane & 15;
    const int n0 = blockIdx.x * 16;              // 50000 = 3125*16
    const int f = wave * 16 + li;

    const int arow = n0 + li;
    const float* Ap = aggr + (size_t)arow * D + q * 8;
    const float* Hp = h + (size_t)arow * D + q * 8;
    const size_t oR = (size_t)f * D + q * 8;
    const size_t oZ = (size_t)(D + f) * D + q * 8;
    const size_t oN = (size_t)(2 * D + f) * D + q * 8;

    float4v accR = {0.f, 0.f, 0.f, 0.f}, accZ = accR, accI = accR, accH = accR;

#pragma unroll
    for (int ks = 0; ks < 4; ++ks) {
        const int off = ks * 32;
        short8 ahi, alo, hhi, hlo;
        split8(Ap + off, ahi, alo);
        split8(Hp + off, hhi, hlo);

        short8 w;
        // r gate: a@WiR + h@WhR
        w = *(const short8*)(Wihi + oR + off);
        accR = __builtin_amdgcn_mfma_f32_16x16x32_bf16(ahi, w, accR, 0, 0, 0);
        accR = __builtin_amdgcn_mfma_f32_16x16x32_bf16(alo, w, accR, 0, 0, 0);
        w = *(const short8*)(Wilo + oR + off);
        accR = __builtin_amdgcn_mfma_f32_16x16x32_bf16(ahi, w, accR, 0, 0, 0);
        w = *(const short8*)(Whhi + oR + off);
        accR = __builtin_amdgcn_mfma_f32_16x16x32_bf16(hhi, w, accR, 0, 0, 0);
        accR = __builtin_amdgcn_mfma_f32_16x16x32_bf16(hlo, w, accR, 0, 0, 0);
        w = *(const short8*)(Whlo + oR + off);
        accR = __builtin_amdgcn_mfma_f32_16x16x32_bf16(hhi, w, accR, 0, 0, 0);
        // z gate
        w = *(const short8*)(Wihi + oZ + off);
        accZ = __builtin_amdgcn_mfma_f32_16x16x32_bf16(ahi, w, accZ, 0, 0, 0);
        accZ = __builtin_amdgcn_mfma_f32_16x16x32_bf16(alo, w, accZ, 0, 0, 0);
        w = *(const short8*)(Wilo + oZ + off);
        accZ = __builtin_amdgcn_mfma_f32_16x16x32_bf16(ahi, w, accZ, 0, 0, 0);
        w = *(const short8*)(Whhi + oZ + off);
        accZ = __builtin_amdgcn_mfma_f32_16x16x32_bf16(hhi, w, accZ, 0, 0, 0);
        accZ = __builtin_amdgcn_mfma_f32_16x16x32_bf16(hlo, w, accZ, 0, 0, 0);
        w = *(const short8*)(Whlo + oZ + off);
        accZ = __builtin_amdgcn_mfma_f32_16x16x32_bf16(hhi, w, accZ, 0, 0, 0);
        // n candidate, input side
        w = *(const short8*)(Wihi + oN + off);
        accI = __builtin_amdgcn_mfma_f32_16x16x32_bf16(ahi, w, accI, 0, 0, 0);
        accI = __builtin_amdgcn_mfma_f32_16x16x32_bf16(alo, w, accI, 0, 0, 0);
        w = *(const short8*)(Wilo + oN + off);
        accI = __builtin_amdgcn_mfma_f32_16x16x32_bf16(ahi, w, accI, 0, 0, 0);
        // n candidate, hidden side
        w = *(const short8*)(Whhi + oN + off);
        accH = __builtin_amdgcn_mfma_f32_16x16x32_bf16(hhi, w, accH, 0, 0, 0);
        accH = __builtin_amdgcn_mfma_f32_16x16x32_bf16(hlo, w, accH, 0, 0, 0);
        w = *(const short8*)(Whlo + oN + off);
        accH = __builtin_amdgcn_mfma_f32_16x16x32_bf16(hhi, w, accH, 0, 0, 0);
    }

    const float bR = b_ih[f] + b_hh[f];
    const float bZ = b_ih[D + f] + b_hh[D + f];
    const float bIn = b_ih[2 * D + f];
    const float bHn = b_hh[2 * D + f];

    const int orow0 = n0 + q * 4;
    float hold[4];
#pragma unroll
    for (int r = 0; r < 4; ++r) hold[r] = h[(size_t)(orow0 + r) * D + f];

    __syncthreads();  // all reads of h complete before any write

#pragma unroll
    for (int r = 0; r < 4; ++r) {
        float rg = 1.0f / (1.0f + __expf(-(accR[r] + bR)));
        float zg = 1.0f / (1.0f + __expf(-(accZ[r] + bZ)));
        float ng = tanhf(accI[r] + bIn + rg * (accH[r] + bHn));
        h[(size_t)(orow0 + r) * D + f] = (1.0f - zg) * ng + zg * hold[r];
    }
}

// ---------------------------------------------------------------------------
extern "C" void kernel_launch(void* const* d_in, const int* in_sizes, int n_in,
                              void* d_out, int out_size, void* d_ws, size_t ws_size,
                              hipStream_t stream) {
    const int* x      = (const int*)d_in[0];
    const int* ei     = (const int*)d_in[1];
    const int* et     = (const int*)d_in[2];
    const int* nt     = (const int*)d_in[3];
    const float* emb  = (const float*)d_in[4];
    const float* Wrel = (const float*)d_in[5];
    const float* b_node = (const float*)d_in[6];
    const float* W_ih = (const float*)d_in[7];
    const float* W_hh = (const float*)d_in[8];
    const float* b_ih = (const float*)d_in[9];
    const float* b_hh = (const float*)d_in[10];

    float* h = (float*)d_out;
    float* ws = (float*)d_ws;

    // Full path needs 58,679,380 floats (234.72 MB); half path 33,079,380 (132.3 MB).
    const bool full = ws_size >= (size_t)58679380 * sizeof(float);
    const size_t HT = full ? 51200000 : 25600000;

    float* Ht = ws;
    float* aggr = ws + HT;                       // 6,400,000 f
    int* deg = (int*)aggr;                       // transient alias (pre-loop only)
    unsigned short* base_us = (unsigned short*)(aggr + 6400000);
    unsigned short* Whi  = base_us;              // 131,072 us
    unsigned short* Wlo  = base_us + 131072;     // 131,072 us
    unsigned short* Wihi = base_us + 262144;     //  49,152 us
    unsigned short* Wilo = base_us + 311296;
    unsigned short* Whhi = base_us + 360448;
    unsigned short* Whlo = base_us + 409600;     // end 458,752 us = 229,376 f
    int* rs     = (int*)(aggr + 6400000 + 229376);  // 50,004
    int* packed = rs + 50004;                       // 800,000

    convert_wrelT<<<512, 256, 0, stream>>>(Wrel, Whi, Wlo);
    convert_w<<<192, 256, 0, stream>>>(W_ih, Wihi, Wilo, 3 * D * D);
    convert_w<<<192, 256, 0, stream>>>(W_hh, Whhi, Whlo, 3 * D * D);
    embed_gather<<<N_NODES, 128, 0, stream>>>(x, emb, h);

    hipMemsetAsync(deg, 0, 50000 * sizeof(int), stream);
    count_deg<<<3125, 256, 0, stream>>>(ei, deg);
    scan_deg<<<1, 1024, 0, stream>>>(deg, rs, deg);   // cursor aliases deg
    fill_csr<<<3125, 256, 0, stream>>>(ei, et, deg, packed);

    for (int it = 0; it < 5; ++it) {
        if (full) {
            dim3 g(782, 8);
            gemm_rel<<<g, 256, 0, stream>>>(h, Whi, Wlo, Ht, 0, 1024);
            aggregate_csr<true, true><<<12500, 256, 0, stream>>>(rs, packed, Ht, nt, b_node, aggr, 0, 1024);
        } else {
            dim3 g(782, 4);
            gemm_rel<<<g, 256, 0, stream>>>(h, Whi, Wlo, Ht, 0, 512);
            aggregate_csr<false, true><<<12500, 256, 0, stream>>>(rs, packed, Ht, nt, b_node, aggr, 0, 512);
            gemm_rel<<<g, 256, 0, stream>>>(h, Whi, Wlo, Ht, 4, 512);
            aggregate_csr<false, false><<<12500, 256, 0, stream>>>(rs, packed, Ht, nt, b_node, aggr, 4, 512);
        }
        gru_mfma<<<3125, 512, 0, stream>>>(aggr, Wihi, Wilo, Whhi, Whlo, b_ih, b_hh, h);
    }
}

// Round 6
// 2136.617 us; speedup vs baseline: 1.2616x; 1.2616x over previous
//
#include <hip/hip_runtime.h>
#include <hip/hip_fp16.h>
#include <math.h>

#define N_NODES 50000
#define N_EDGES 800000
#define D 128
#define T_TYPES 8

typedef short short8 __attribute__((ext_vector_type(8)));
typedef float float4v __attribute__((ext_vector_type(4)));
typedef unsigned short ushort_t;

static __device__ __forceinline__ unsigned short f2bf(float f) {
    unsigned u = __float_as_uint(f);
    u += 0x7fff + ((u >> 16) & 1);   // round-to-nearest-even
    return (unsigned short)(u >> 16);
}
static __device__ __forceinline__ float bf2f(unsigned short b) {
    return __uint_as_float((unsigned)b << 16);
}
// exact two-term split: x ~= hi + lo, error <= 2^-18 |x|
static __device__ __forceinline__ void splitbf(float x, unsigned short& hi, unsigned short& lo) {
    unsigned short h_ = f2bf(x);
    hi = h_;
    lo = f2bf(x - bf2f(h_));
}

// ---------------------------------------------------------------------------
// h[n][d] = emb[x[n]][d] (fp32) + pre-split hi/lo bf16 copies
__global__ void embed_gather(const int* __restrict__ x, const float* __restrict__ emb,
                             float* __restrict__ h,
                             ushort_t* __restrict__ hhi, ushort_t* __restrict__ hlo) {
    int n = blockIdx.x;
    int d = threadIdx.x;
    float v = emb[(size_t)x[n] * D + d];
    h[(size_t)n * D + d] = v;
    unsigned short a, b;
    splitbf(v, a, b);
    hhi[(size_t)n * D + d] = a;
    hlo[(size_t)n * D + d] = b;
}

// WrelT[t][f][d] = Wrel[t][d][f], split hi/lo bf16
__global__ void convert_wrelT(const float* __restrict__ Wrel,
                              ushort_t* __restrict__ hi, ushort_t* __restrict__ lo) {
    int idx = blockIdx.x * 256 + threadIdx.x; // 0..131071
    int t = idx >> 14;
    int rem = idx & 16383;
    int f = rem >> 7;
    int d = rem & 127;
    unsigned short a, b;
    splitbf(Wrel[((size_t)t << 14) + (d << 7) + f], a, b);
    hi[idx] = a;
    lo[idx] = b;
}

// GRU weights keep [3D][D] layout (already B^T form), split hi/lo
__global__ void convert_w(const float* __restrict__ in,
                          ushort_t* __restrict__ hi, ushort_t* __restrict__ lo, int n) {
    int idx = blockIdx.x * 256 + threadIdx.x;
    if (idx < n) {
        unsigned short a, b;
        splitbf(in[idx], a, b);
        hi[idx] = a;
        lo[idx] = b;
    }
}

// ---------------------------------------------------------------------------
// CSR build over dst
__global__ void count_deg(const int* __restrict__ ei, int* __restrict__ deg) {
    int e = blockIdx.x * 256 + threadIdx.x;
    if (e >= N_EDGES) return;
    atomicAdd(&deg[ei[N_EDGES + e]], 1);
}

__global__ __launch_bounds__(1024) void scan_deg(const int* __restrict__ deg,
                                                 int* __restrict__ rs,
                                                 int* __restrict__ cursor) {
    __shared__ int sums[1024];
    const int tid = threadIdx.x;
    const int CH = 49;
    const int base = tid * CH;
    int s = 0;
    for (int i = 0; i < CH; ++i) {
        int idx = base + i;
        if (idx < N_NODES) s += deg[idx];
    }
    sums[tid] = s;
    __syncthreads();
    for (int ofs = 1; ofs < 1024; ofs <<= 1) {
        int v = (tid >= ofs) ? sums[tid - ofs] : 0;
        __syncthreads();
        sums[tid] += v;
        __syncthreads();
    }
    int run = sums[tid] - s;
    for (int i = 0; i < CH; ++i) {
        int idx = base + i;
        if (idx < N_NODES) {
            int dv = deg[idx];      // read BEFORE cursor write (cursor aliases deg)
            rs[idx] = run;
            cursor[idx] = run;
            run += dv;
        }
    }
    if (tid == 0) rs[N_NODES] = N_EDGES;
}

__global__ void fill_csr(const int* __restrict__ ei, const int* __restrict__ et,
                         int* __restrict__ cursor, int* __restrict__ packed) {
    int e = blockIdx.x * 256 + threadIdx.x;
    if (e >= N_EDGES) return;
    int dst = ei[N_EDGES + e];
    int pos = atomicAdd(&cursor[dst], 1);
    packed[pos] = (ei[e] << 3) | et[e];
}

// ---------------------------------------------------------------------------
// Relational transform, bf16x3 MFMA, fp16 output via LDS-staged coalesced stores.
// Block 256 thr = 4 waves; wave covers 16 rows x 128 cols of type blockIdx.y.
__global__ __launch_bounds__(256) void gemm_rel(const ushort_t* __restrict__ hhi,
                                                const ushort_t* __restrict__ hlo,
                                                const ushort_t* __restrict__ Whi,
                                                const ushort_t* __restrict__ Wlo,
                                                ushort_t* __restrict__ Ht) {
    __shared__ ushort_t tile[4][2048];   // 16x128 fp16 per wave, 16 KB total
    const int tid = threadIdx.x;
    const int wave = tid >> 6, lane = tid & 63;
    const int q = lane >> 4, li = lane & 15;
    const int m_base = blockIdx.x * 64 + wave * 16;
    const int t = blockIdx.y;

    int arow = m_base + li;
    if (arow > N_NODES - 1) arow = N_NODES - 1;
    const ushort_t* Ah = hhi + (size_t)arow * D + q * 8;
    const ushort_t* Al = hlo + (size_t)arow * D + q * 8;
    const size_t boff = ((size_t)t << 14) + (size_t)li * D + q * 8;
    const ushort_t* Bh = Whi + boff;
    const ushort_t* Bl = Wlo + boff;

    float4v acc[8];
#pragma unroll
    for (int ft = 0; ft < 8; ++ft) acc[ft] = (float4v){0.f, 0.f, 0.f, 0.f};

#pragma unroll
    for (int ks = 0; ks < 4; ++ks) {
        short8 ahi_ = *(const short8*)(Ah + ks * 32);
        short8 alo_ = *(const short8*)(Al + ks * 32);
#pragma unroll
        for (int ft = 0; ft < 8; ++ft) {
            short8 bh = *(const short8*)(Bh + ft * 2048 + ks * 32);
            short8 bl = *(const short8*)(Bl + ft * 2048 + ks * 32);
            acc[ft] = __builtin_amdgcn_mfma_f32_16x16x32_bf16(ahi_, bh, acc[ft], 0, 0, 0);
            acc[ft] = __builtin_amdgcn_mfma_f32_16x16x32_bf16(alo_, bh, acc[ft], 0, 0, 0);
            acc[ft] = __builtin_amdgcn_mfma_f32_16x16x32_bf16(ahi_, bl, acc[ft], 0, 0, 0);
        }
    }

    // epilogue: fp16 into wave-private LDS tile, then coalesced dwordx4 stores
    ushort_t* tw = tile[wave];
#pragma unroll
    for (int ft = 0; ft < 8; ++ft) {
#pragma unroll
        for (int r = 0; r < 4; ++r) {
            __half hv = __float2half_rn(acc[ft][r]);
            tw[(q * 4 + r) * 128 + ft * 16 + li] = __half_as_ushort(hv);
        }
    }
    // wave-local LDS round-trip: compiler inserts lgkmcnt wait; no barrier needed
#pragma unroll
    for (int i = 0; i < 4; ++i) {
        int idx = i * 512 + lane * 8;   // ushort index into 16x128 tile
        int row = idx >> 7;
        int col = idx & 127;
        short8 v = *(const short8*)(tw + idx);
        int orow = m_base + row;
        if (orow < N_NODES)
            *(short8*)(Ht + (size_t)orow * 1024 + (t << 7) + col) = v;
    }
}

// ---------------------------------------------------------------------------
// CSR aggregation: one wave per dst node; fp16 Ht gather, fp32 accumulate,
// pre-split bf16 hi/lo output. Fuses b_node bias.
__global__ __launch_bounds__(256) void aggregate_csr(const int* __restrict__ rs,
                                                     const int* __restrict__ packed,
                                                     const ushort_t* __restrict__ Ht,
                                                     const int* __restrict__ nt,
                                                     const float* __restrict__ b_node,
                                                     ushort_t* __restrict__ ahi,
                                                     ushort_t* __restrict__ alo) {
    int n = blockIdx.x * 4 + (threadIdx.x >> 6);
    if (n >= N_NODES) return;
    const int lane = threadIdx.x & 63;
    const int beg = rs[n], end = rs[n + 1];
    const __half2* Ht2 = (const __half2*)Ht;

    float2 acc = ((const float2*)(b_node + (size_t)nt[n] * D))[lane];

    int i = beg;
    for (; i + 3 < end; i += 4) {
        int p0 = packed[i], p1 = packed[i + 1], p2 = packed[i + 2], p3 = packed[i + 3];
        float2 f0 = __half22float2(Ht2[(size_t)p0 * 64 + lane]);
        float2 f1 = __half22float2(Ht2[(size_t)p1 * 64 + lane]);
        float2 f2 = __half22float2(Ht2[(size_t)p2 * 64 + lane]);
        float2 f3 = __half22float2(Ht2[(size_t)p3 * 64 + lane]);
        acc.x += (f0.x + f1.x) + (f2.x + f3.x);
        acc.y += (f0.y + f1.y) + (f2.y + f3.y);
    }
    for (; i < end; ++i) {
        int pk = packed[i];
        float2 fv = __half22float2(Ht2[(size_t)pk * 64 + lane]);
        acc.x += fv.x;
        acc.y += fv.y;
    }

    unsigned short h0, l0, h1, l1;
    splitbf(acc.x, h0, l0);
    splitbf(acc.y, h1, l1);
    ((unsigned*)ahi)[(size_t)n * 64 + lane] = (unsigned)h0 | ((unsigned)h1 << 16);
    ((unsigned*)alo)[(size_t)n * 64 + lane] = (unsigned)l0 | ((unsigned)l1 << 16);
}

// ---------------------------------------------------------------------------
// Fused GRU, bf16x3 MFMA. Block = 512 thr = 8 waves; block owns 64 rows x 128 cols.
// Wave w covers f-tile w*16 for 4 m-subtiles; weight frags loaded once per k-step
// and reused across the 4 m-tiles. All reads precede __syncthreads(); writes after.
__global__ __launch_bounds__(512) void gru_mfma(const ushort_t* __restrict__ ahi,
                                                const ushort_t* __restrict__ alo,
                                                ushort_t* __restrict__ hhi,
                                                ushort_t* __restrict__ hlo,
                                                const ushort_t* __restrict__ Wihi,
                                                const ushort_t* __restrict__ Wilo,
                                                const ushort_t* __restrict__ Whhi,
                                                const ushort_t* __restrict__ Whlo,
                                                const float* __restrict__ b_ih,
                                                const float* __restrict__ b_hh,
                                                float* __restrict__ h) {
    const int tid = threadIdx.x;
    const int wave = tid >> 6, lane = tid & 63;
    const int q = lane >> 4, li = lane & 15;
    const int n0 = blockIdx.x * 64;
    const int f = wave * 16 + li;

    size_t rowoff[4];
#pragma unroll
    for (int m = 0; m < 4; ++m) {
        int ar = n0 + m * 16 + li;
        if (ar > N_NODES - 1) ar = N_NODES - 1;
        rowoff[m] = (size_t)ar * D + q * 8;
    }
    const size_t oR = (size_t)f * D + q * 8;
    const size_t oZ = (size_t)(D + f) * D + q * 8;
    const size_t oN = (size_t)(2 * D + f) * D + q * 8;

    float4v aR[4], aZ[4], aI[4], aH[4];
#pragma unroll
    for (int m = 0; m < 4; ++m) {
        aR[m] = (float4v){0.f, 0.f, 0.f, 0.f};
        aZ[m] = aR[m]; aI[m] = aR[m]; aH[m] = aR[m];
    }

#pragma unroll
    for (int ks = 0; ks < 4; ++ks) {
        const int off = ks * 32;
        short8 wIRh = *(const short8*)(Wihi + oR + off);
        short8 wIRl = *(const short8*)(Wilo + oR + off);
        short8 wHRh = *(const short8*)(Whhi + oR + off);
        short8 wHRl = *(const short8*)(Whlo + oR + off);
        short8 wIZh = *(const short8*)(Wihi + oZ + off);
        short8 wIZl = *(const short8*)(Wilo + oZ + off);
        short8 wHZh = *(const short8*)(Whhi + oZ + off);
        short8 wHZl = *(const short8*)(Whlo + oZ + off);
        short8 wINh = *(const short8*)(Wihi + oN + off);
        short8 wINl = *(const short8*)(Wilo + oN + off);
        short8 wHNh = *(const short8*)(Whhi + oN + off);
        short8 wHNl = *(const short8*)(Whlo + oN + off);
#pragma unroll
        for (int m = 0; m < 4; ++m) {
            const size_t ro = rowoff[m] + off;
            short8 xah = *(const short8*)(ahi + ro);
            short8 xal = *(const short8*)(alo + ro);
            short8 xhh = *(const short8*)(hhi + ro);
            short8 xhl = *(const short8*)(hlo + ro);
            aR[m] = __builtin_amdgcn_mfma_f32_16x16x32_bf16(xah, wIRh, aR[m], 0, 0, 0);
            aR[m] = __builtin_amdgcn_mfma_f32_16x16x32_bf16(xal, wIRh, aR[m], 0, 0, 0);
            aR[m] = __builtin_amdgcn_mfma_f32_16x16x32_bf16(xah, wIRl, aR[m], 0, 0, 0);
            aR[m] = __builtin_amdgcn_mfma_f32_16x16x32_bf16(xhh, wHRh, aR[m], 0, 0, 0);
            aR[m] = __builtin_amdgcn_mfma_f32_16x16x32_bf16(xhl, wHRh, aR[m], 0, 0, 0);
            aR[m] = __builtin_amdgcn_mfma_f32_16x16x32_bf16(xhh, wHRl, aR[m], 0, 0, 0);
            aZ[m] = __builtin_amdgcn_mfma_f32_16x16x32_bf16(xah, wIZh, aZ[m], 0, 0, 0);
            aZ[m] = __builtin_amdgcn_mfma_f32_16x16x32_bf16(xal, wIZh, aZ[m], 0, 0, 0);
            aZ[m] = __builtin_amdgcn_mfma_f32_16x16x32_bf16(xah, wIZl, aZ[m], 0, 0, 0);
            aZ[m] = __builtin_amdgcn_mfma_f32_16x16x32_bf16(xhh, wHZh, aZ[m], 0, 0, 0);
            aZ[m] = __builtin_amdgcn_mfma_f32_16x16x32_bf16(xhl, wHZh, aZ[m], 0, 0, 0);
            aZ[m] = __builtin_amdgcn_mfma_f32_16x16x32_bf16(xhh, wHZl, aZ[m], 0, 0, 0);
            aI[m] = __builtin_amdgcn_mfma_f32_16x16x32_bf16(xah, wINh, aI[m], 0, 0, 0);
            aI[m] = __builtin_amdgcn_mfma_f32_16x16x32_bf16(xal, wINh, aI[m], 0, 0, 0);
            aI[m] = __builtin_amdgcn_mfma_f32_16x16x32_bf16(xah, wINl, aI[m], 0, 0, 0);
            aH[m] = __builtin_amdgcn_mfma_f32_16x16x32_bf16(xhh, wHNh, aH[m], 0, 0, 0);
            aH[m] = __builtin_amdgcn_mfma_f32_16x16x32_bf16(xhl, wHNh, aH[m], 0, 0, 0);
            aH[m] = __builtin_amdgcn_mfma_f32_16x16x32_bf16(xhh, wHNl, aH[m], 0, 0, 0);
        }
    }

    const float bR = b_ih[f] + b_hh[f];
    const float bZ = b_ih[D + f] + b_hh[D + f];
    const float bIn = b_ih[2 * D + f];
    const float bHn = b_hh[2 * D + f];

    float hold[4][4];
#pragma unroll
    for (int m = 0; m < 4; ++m) {
#pragma unroll
        for (int r = 0; r < 4; ++r) {
            int node = n0 + m * 16 + q * 4 + r;
            if (node > N_NODES - 1) node = N_NODES - 1;
            hold[m][r] = h[(size_t)node * D + f];
        }
    }

    __syncthreads();  // all reads of h/hhi/hlo complete before any write

#pragma unroll
    for (int m = 0; m < 4; ++m) {
#pragma unroll
        for (int r = 0; r < 4; ++r) {
            int node = n0 + m * 16 + q * 4 + r;
            if (node < N_NODES) {
                float rg = 1.0f / (1.0f + __expf(-(aR[m][r] + bR)));
                float zg = 1.0f / (1.0f + __expf(-(aZ[m][r] + bZ)));
                float narg = aI[m][r] + bIn + rg * (aH[m][r] + bHn);
                float ex = __expf(2.0f * narg);
                float ng = 1.0f - 2.0f / (ex + 1.0f);   // tanh
                float hn = (1.0f - zg) * ng + zg * hold[m][r];
                h[(size_t)node * D + f] = hn;
                unsigned short sh, sl;
                splitbf(hn, sh, sl);
                hhi[(size_t)node * D + f] = sh;
                hlo[(size_t)node * D + f] = sl;
            }
        }
    }
}

// ---------------------------------------------------------------------------
extern "C" void kernel_launch(void* const* d_in, const int* in_sizes, int n_in,
                              void* d_out, int out_size, void* d_ws, size_t ws_size,
                              hipStream_t stream) {
    const int* x      = (const int*)d_in[0];
    const int* ei     = (const int*)d_in[1];
    const int* et     = (const int*)d_in[2];
    const int* nt     = (const int*)d_in[3];
    const float* emb  = (const float*)d_in[4];
    const float* Wrel = (const float*)d_in[5];
    const float* b_node = (const float*)d_in[6];
    const float* W_ih = (const float*)d_in[7];
    const float* W_hh = (const float*)d_in[8];
    const float* b_ih = (const float*)d_in[9];
    const float* b_hh = (const float*)d_in[10];

    float* h = (float*)d_out;
    float* ws = (float*)d_ws;

    // workspace layout (total 157.9 MB, well under proven >=234 MB)
    ushort_t* Ht = (ushort_t*)ws;                          // 51,200,000 us (fp16)
    ushort_t* us = (ushort_t*)(ws + 25600000);
    ushort_t* ahi  = us;                                   // 6,400,000 each
    ushort_t* alo  = us + 6400000;
    ushort_t* hhi  = us + 12800000;
    ushort_t* hlo  = us + 19200000;
    ushort_t* Whi  = us + 25600000;                        //   131,072 each
    ushort_t* Wlo  = Whi + 131072;
    ushort_t* Wihi = Wlo + 131072;                         //    49,152 each
    ushort_t* Wilo = Wihi + 49152;
    ushort_t* Whhi = Wilo + 49152;
    ushort_t* Whlo = Whhi + 49152;
    int* rs     = (int*)(ws + 38629376);                   //    50,004
    int* packed = rs + 50004;                              //   800,000
    int* deg    = (int*)ws;                                // transient alias in Ht region (pre-loop only)

    convert_wrelT<<<512, 256, 0, stream>>>(Wrel, Whi, Wlo);
    convert_w<<<192, 256, 0, stream>>>(W_ih, Wihi, Wilo, 3 * D * D);
    convert_w<<<192, 256, 0, stream>>>(W_hh, Whhi, Whlo, 3 * D * D);
    embed_gather<<<N_NODES, 128, 0, stream>>>(x, emb, h, hhi, hlo);

    hipMemsetAsync(deg, 0, 50000 * sizeof(int), stream);
    count_deg<<<3125, 256, 0, stream>>>(ei, deg);
    scan_deg<<<1, 1024, 0, stream>>>(deg, rs, deg);   // cursor aliases deg
    fill_csr<<<3125, 256, 0, stream>>>(ei, et, deg, packed);

    for (int it = 0; it < 5; ++it) {
        dim3 g(782, T_TYPES);
        gemm_rel<<<g, 256, 0, stream>>>(hhi, hlo, Whi, Wlo, Ht);
        aggregate_csr<<<12500, 256, 0, stream>>>(rs, packed, Ht, nt, b_node, ahi, alo);
        gru_mfma<<<782, 512, 0, stream>>>(ahi, alo, hhi, hlo,
                                          Wihi, Wilo, Whhi, Whlo, b_ih, b_hh, h);
    }
}

// Round 7
// 2121.248 us; speedup vs baseline: 1.2707x; 1.0072x over previous
//
#include <hip/hip_runtime.h>
#include <hip/hip_fp16.h>
#include <math.h>

#define N_NODES 50000
#define N_EDGES 800000
#define D 128
#define T_TYPES 8

typedef short short8 __attribute__((ext_vector_type(8)));
typedef float float4v __attribute__((ext_vector_type(4)));
typedef unsigned short ushort_t;

static __device__ __forceinline__ unsigned short f2bf(float f) {
    unsigned u = __float_as_uint(f);
    u += 0x7fff + ((u >> 16) & 1);   // round-to-nearest-even
    return (unsigned short)(u >> 16);
}
static __device__ __forceinline__ float bf2f(unsigned short b) {
    return __uint_as_float((unsigned)b << 16);
}
// exact two-term split: x ~= hi + lo, error <= 2^-18 |x|
static __device__ __forceinline__ void splitbf(float x, unsigned short& hi, unsigned short& lo) {
    unsigned short h_ = f2bf(x);
    hi = h_;
    lo = f2bf(x - bf2f(h_));
}

// ---------------------------------------------------------------------------
// h[n][d] = emb[x[n]][d] (fp32) + pre-split hi/lo bf16 copies
__global__ void embed_gather(const int* __restrict__ x, const float* __restrict__ emb,
                             float* __restrict__ h,
                             ushort_t* __restrict__ hhi, ushort_t* __restrict__ hlo) {
    int n = blockIdx.x;
    int d = threadIdx.x;
    float v = emb[(size_t)x[n] * D + d];
    h[(size_t)n * D + d] = v;
    unsigned short a, b;
    splitbf(v, a, b);
    hhi[(size_t)n * D + d] = a;
    hlo[(size_t)n * D + d] = b;
}

// WrelT[t][f][d] = Wrel[t][d][f], split hi/lo bf16
__global__ void convert_wrelT(const float* __restrict__ Wrel,
                              ushort_t* __restrict__ hi, ushort_t* __restrict__ lo) {
    int idx = blockIdx.x * 256 + threadIdx.x; // 0..131071
    int t = idx >> 14;
    int rem = idx & 16383;
    int f = rem >> 7;
    int d = rem & 127;
    unsigned short a, b;
    splitbf(Wrel[((size_t)t << 14) + (d << 7) + f], a, b);
    hi[idx] = a;
    lo[idx] = b;
}

// GRU weights keep [3D][D] layout (already B^T form), split hi/lo
__global__ void convert_w(const float* __restrict__ in,
                          ushort_t* __restrict__ hi, ushort_t* __restrict__ lo, int n) {
    int idx = blockIdx.x * 256 + threadIdx.x;
    if (idx < n) {
        unsigned short a, b;
        splitbf(in[idx], a, b);
        hi[idx] = a;
        lo[idx] = b;
    }
}

// ---------------------------------------------------------------------------
// CSR build over dst
__global__ void count_deg(const int* __restrict__ ei, int* __restrict__ deg) {
    int e = blockIdx.x * 256 + threadIdx.x;
    if (e >= N_EDGES) return;
    atomicAdd(&deg[ei[N_EDGES + e]], 1);
}

__global__ __launch_bounds__(1024) void scan_deg(const int* __restrict__ deg,
                                                 int* __restrict__ rs,
                                                 int* __restrict__ cursor) {
    __shared__ int sums[1024];
    const int tid = threadIdx.x;
    const int CH = 49;
    const int base = tid * CH;
    int s = 0;
    for (int i = 0; i < CH; ++i) {
        int idx = base + i;
        if (idx < N_NODES) s += deg[idx];
    }
    sums[tid] = s;
    __syncthreads();
    for (int ofs = 1; ofs < 1024; ofs <<= 1) {
        int v = (tid >= ofs) ? sums[tid - ofs] : 0;
        __syncthreads();
        sums[tid] += v;
        __syncthreads();
    }
    int run = sums[tid] - s;
    for (int i = 0; i < CH; ++i) {
        int idx = base + i;
        if (idx < N_NODES) {
            int dv = deg[idx];      // read BEFORE cursor write (cursor aliases deg)
            rs[idx] = run;
            cursor[idx] = run;
            run += dv;
        }
    }
    if (tid == 0) rs[N_NODES] = N_EDGES;
}

__global__ void fill_csr(const int* __restrict__ ei, const int* __restrict__ et,
                         int* __restrict__ cursor, int* __restrict__ packed) {
    int e = blockIdx.x * 256 + threadIdx.x;
    if (e >= N_EDGES) return;
    int dst = ei[N_EDGES + e];
    int pos = atomicAdd(&cursor[dst], 1);
    packed[pos] = (ei[e] << 3) | et[e];
}

// ---------------------------------------------------------------------------
// Relational transform, bf16x3 MFMA, fp16 output via LDS-staged coalesced stores.
// Block 256 thr = 4 waves; wave covers 16 rows x 128 cols of type blockIdx.y.
// launch_bounds(256,2): VGPR cap 256 so the 16 B-frag loads per k-step stay in
// flight (R6's VGPR=56 serialized every load -> 21K cyc/wave with all pipes idle).
#define TPAD 136   // LDS tile row stride (ushorts): 272 B = 17 banks-of-16B -> uniform
__global__ __launch_bounds__(256, 2) void gemm_rel(const ushort_t* __restrict__ hhi,
                                                   const ushort_t* __restrict__ hlo,
                                                   const ushort_t* __restrict__ Whi,
                                                   const ushort_t* __restrict__ Wlo,
                                                   ushort_t* __restrict__ Ht) {
    __shared__ ushort_t tile[4][16 * TPAD];   // 16x128 fp16 per wave (padded)
    const int tid = threadIdx.x;
    const int wave = tid >> 6, lane = tid & 63;
    const int q = lane >> 4, li = lane & 15;
    const int m_base = blockIdx.x * 64 + wave * 16;
    const int t = blockIdx.y;

    int arow = m_base + li;
    if (arow > N_NODES - 1) arow = N_NODES - 1;
    const ushort_t* Ah = hhi + (size_t)arow * D + q * 8;
    const ushort_t* Al = hlo + (size_t)arow * D + q * 8;
    const size_t boff = ((size_t)t << 14) + (size_t)li * D + q * 8;
    const ushort_t* Bh = Whi + boff;
    const ushort_t* Bl = Wlo + boff;

    float4v acc[8];
#pragma unroll
    for (int ft = 0; ft < 8; ++ft) acc[ft] = (float4v){0.f, 0.f, 0.f, 0.f};

#pragma unroll
    for (int ks = 0; ks < 4; ++ks) {
        // batch ALL loads for this k-step first -> 18 independent loads in flight
        short8 a_hi = *(const short8*)(Ah + ks * 32);
        short8 a_lo = *(const short8*)(Al + ks * 32);
        short8 bh[8], bl[8];
#pragma unroll
        for (int ft = 0; ft < 8; ++ft) {
            bh[ft] = *(const short8*)(Bh + ft * 2048 + ks * 32);
            bl[ft] = *(const short8*)(Bl + ft * 2048 + ks * 32);
        }
#pragma unroll
        for (int ft = 0; ft < 8; ++ft) {
            acc[ft] = __builtin_amdgcn_mfma_f32_16x16x32_bf16(a_hi, bh[ft], acc[ft], 0, 0, 0);
            acc[ft] = __builtin_amdgcn_mfma_f32_16x16x32_bf16(a_lo, bh[ft], acc[ft], 0, 0, 0);
            acc[ft] = __builtin_amdgcn_mfma_f32_16x16x32_bf16(a_hi, bl[ft], acc[ft], 0, 0, 0);
        }
    }

    // epilogue: fp16 into wave-private padded LDS tile, then coalesced stores
    ushort_t* tw = tile[wave];
#pragma unroll
    for (int ft = 0; ft < 8; ++ft) {
#pragma unroll
        for (int r = 0; r < 4; ++r) {
            __half hv = __float2half_rn(acc[ft][r]);
            tw[(q * 4 + r) * TPAD + ft * 16 + li] = __half_as_ushort(hv);
        }
    }
    // wave-local LDS round-trip: compiler inserts lgkmcnt wait; no barrier needed
#pragma unroll
    for (int i = 0; i < 4; ++i) {
        int row = i * 4 + q;
        int col = li * 8;
        short8 v = *(const short8*)(tw + row * TPAD + col);
        int orow = m_base + row;
        if (orow < N_NODES)
            *(short8*)(Ht + (size_t)orow * 1024 + (t << 7) + col) = v;
    }
}

// ---------------------------------------------------------------------------
// CSR aggregation: one wave per dst node; fp16 Ht gather, fp32 accumulate,
// pre-split bf16 hi/lo output. Fuses b_node bias.
__global__ __launch_bounds__(256) void aggregate_csr(const int* __restrict__ rs,
                                                     const int* __restrict__ packed,
                                                     const ushort_t* __restrict__ Ht,
                                                     const int* __restrict__ nt,
                                                     const float* __restrict__ b_node,
                                                     ushort_t* __restrict__ ahi,
                                                     ushort_t* __restrict__ alo) {
    int n = blockIdx.x * 4 + (threadIdx.x >> 6);
    if (n >= N_NODES) return;
    const int lane = threadIdx.x & 63;
    const int beg = rs[n], end = rs[n + 1];
    const __half2* Ht2 = (const __half2*)Ht;

    float2 acc = ((const float2*)(b_node + (size_t)nt[n] * D))[lane];

    int i = beg;
    for (; i + 3 < end; i += 4) {
        int p0 = packed[i], p1 = packed[i + 1], p2 = packed[i + 2], p3 = packed[i + 3];
        float2 f0 = __half22float2(Ht2[(size_t)p0 * 64 + lane]);
        float2 f1 = __half22float2(Ht2[(size_t)p1 * 64 + lane]);
        float2 f2 = __half22float2(Ht2[(size_t)p2 * 64 + lane]);
        float2 f3 = __half22float2(Ht2[(size_t)p3 * 64 + lane]);
        acc.x += (f0.x + f1.x) + (f2.x + f3.x);
        acc.y += (f0.y + f1.y) + (f2.y + f3.y);
    }
    for (; i < end; ++i) {
        int pk = packed[i];
        float2 fv = __half22float2(Ht2[(size_t)pk * 64 + lane]);
        acc.x += fv.x;
        acc.y += fv.y;
    }

    unsigned short h0, l0, h1, l1;
    splitbf(acc.x, h0, l0);
    splitbf(acc.y, h1, l1);
    ((unsigned*)ahi)[(size_t)n * 64 + lane] = (unsigned)h0 | ((unsigned)h1 << 16);
    ((unsigned*)alo)[(size_t)n * 64 + lane] = (unsigned)l0 | ((unsigned)l1 << 16);
}

// ---------------------------------------------------------------------------
// Fused GRU, bf16x3 MFMA. Block = 512 thr = 8 waves; block owns 64 rows x 128 cols.
// launch_bounds(512,2): VGPR cap 256 so the 12 weight frags stay resident per
// k-step and the 4 x-frag loads per m-tile overlap the MFMA burst.
__global__ __launch_bounds__(512, 2) void gru_mfma(const ushort_t* __restrict__ ahi,
                                                   const ushort_t* __restrict__ alo,
                                                   ushort_t* __restrict__ hhi,
                                                   ushort_t* __restrict__ hlo,
                                                   const ushort_t* __restrict__ Wihi,
                                                   const ushort_t* __restrict__ Wilo,
                                                   const ushort_t* __restrict__ Whhi,
                                                   const ushort_t* __restrict__ Whlo,
                                                   const float* __restrict__ b_ih,
                                                   const float* __restrict__ b_hh,
                                                   float* __restrict__ h) {
    const int tid = threadIdx.x;
    const int wave = tid >> 6, lane = tid & 63;
    const int q = lane >> 4, li = lane & 15;
    const int n0 = blockIdx.x * 64;
    const int f = wave * 16 + li;

    size_t rowoff[4];
#pragma unroll
    for (int m = 0; m < 4; ++m) {
        int ar = n0 + m * 16 + li;
        if (ar > N_NODES - 1) ar = N_NODES - 1;
        rowoff[m] = (size_t)ar * D + q * 8;
    }
    const size_t oR = (size_t)f * D + q * 8;
    const size_t oZ = (size_t)(D + f) * D + q * 8;
    const size_t oN = (size_t)(2 * D + f) * D + q * 8;

    float4v aR[4], aZ[4], aI[4], aH[4];
#pragma unroll
    for (int m = 0; m < 4; ++m) {
        aR[m] = (float4v){0.f, 0.f, 0.f, 0.f};
        aZ[m] = aR[m]; aI[m] = aR[m]; aH[m] = aR[m];
    }

#pragma unroll
    for (int ks = 0; ks < 4; ++ks) {
        const int off = ks * 32;
        short8 wIRh = *(const short8*)(Wihi + oR + off);
        short8 wIRl = *(const short8*)(Wilo + oR + off);
        short8 wHRh = *(const short8*)(Whhi + oR + off);
        short8 wHRl = *(const short8*)(Whlo + oR + off);
        short8 wIZh = *(const short8*)(Wihi + oZ + off);
        short8 wIZl = *(const short8*)(Wilo + oZ + off);
        short8 wHZh = *(const short8*)(Whhi + oZ + off);
        short8 wHZl = *(const short8*)(Whlo + oZ + off);
        short8 wINh = *(const short8*)(Wihi + oN + off);
        short8 wINl = *(const short8*)(Wilo + oN + off);
        short8 wHNh = *(const short8*)(Whhi + oN + off);
        short8 wHNl = *(const short8*)(Whlo + oN + off);
#pragma unroll
        for (int m = 0; m < 4; ++m) {
            const size_t ro = rowoff[m] + off;
            short8 xah = *(const short8*)(ahi + ro);
            short8 xal = *(const short8*)(alo + ro);
            short8 xhh = *(const short8*)(hhi + ro);
            short8 xhl = *(const short8*)(hlo + ro);
            aR[m] = __builtin_amdgcn_mfma_f32_16x16x32_bf16(xah, wIRh, aR[m], 0, 0, 0);
            aR[m] = __builtin_amdgcn_mfma_f32_16x16x32_bf16(xal, wIRh, aR[m], 0, 0, 0);
            aR[m] = __builtin_amdgcn_mfma_f32_16x16x32_bf16(xah, wIRl, aR[m], 0, 0, 0);
            aR[m] = __builtin_amdgcn_mfma_f32_16x16x32_bf16(xhh, wHRh, aR[m], 0, 0, 0);
            aR[m] = __builtin_amdgcn_mfma_f32_16x16x32_bf16(xhl, wHRh, aR[m], 0, 0, 0);
            aR[m] = __builtin_amdgcn_mfma_f32_16x16x32_bf16(xhh, wHRl, aR[m], 0, 0, 0);
            aZ[m] = __builtin_amdgcn_mfma_f32_16x16x32_bf16(xah, wIZh, aZ[m], 0, 0, 0);
            aZ[m] = __builtin_amdgcn_mfma_f32_16x16x32_bf16(xal, wIZh, aZ[m], 0, 0, 0);
            aZ[m] = __builtin_amdgcn_mfma_f32_16x16x32_bf16(xah, wIZl, aZ[m], 0, 0, 0);
            aZ[m] = __builtin_amdgcn_mfma_f32_16x16x32_bf16(xhh, wHZh, aZ[m], 0, 0, 0);
            aZ[m] = __builtin_amdgcn_mfma_f32_16x16x32_bf16(xhl, wHZh, aZ[m], 0, 0, 0);
            aZ[m] = __builtin_amdgcn_mfma_f32_16x16x32_bf16(xhh, wHZl, aZ[m], 0, 0, 0);
            aI[m] = __builtin_amdgcn_mfma_f32_16x16x32_bf16(xah, wINh, aI[m], 0, 0, 0);
            aI[m] = __builtin_amdgcn_mfma_f32_16x16x32_bf16(xal, wINh, aI[m], 0, 0, 0);
            aI[m] = __builtin_amdgcn_mfma_f32_16x16x32_bf16(xah, wINl, aI[m], 0, 0, 0);
            aH[m] = __builtin_amdgcn_mfma_f32_16x16x32_bf16(xhh, wHNh, aH[m], 0, 0, 0);
            aH[m] = __builtin_amdgcn_mfma_f32_16x16x32_bf16(xhl, wHNh, aH[m], 0, 0, 0);
            aH[m] = __builtin_amdgcn_mfma_f32_16x16x32_bf16(xhh, wHNl, aH[m], 0, 0, 0);
        }
    }

    const float bR = b_ih[f] + b_hh[f];
    const float bZ = b_ih[D + f] + b_hh[D + f];
    const float bIn = b_ih[2 * D + f];
    const float bHn = b_hh[2 * D + f];

    float hold[4][4];
#pragma unroll
    for (int m = 0; m < 4; ++m) {
#pragma unroll
        for (int r = 0; r < 4; ++r) {
            int node = n0 + m * 16 + q * 4 + r;
            if (node > N_NODES - 1) node = N_NODES - 1;
            hold[m][r] = h[(size_t)node * D + f];
        }
    }

    __syncthreads();  // all reads of h/hhi/hlo complete before any write

#pragma unroll
    for (int m = 0; m < 4; ++m) {
#pragma unroll
        for (int r = 0; r < 4; ++r) {
            int node = n0 + m * 16 + q * 4 + r;
            if (node < N_NODES) {
                float rg = 1.0f / (1.0f + __expf(-(aR[m][r] + bR)));
                float zg = 1.0f / (1.0f + __expf(-(aZ[m][r] + bZ)));
                float narg = aI[m][r] + bIn + rg * (aH[m][r] + bHn);
                float ex = __expf(2.0f * narg);
                float ng = 1.0f - 2.0f / (ex + 1.0f);   // tanh
                float hn = (1.0f - zg) * ng + zg * hold[m][r];
                h[(size_t)node * D + f] = hn;
                unsigned short sh, sl;
                splitbf(hn, sh, sl);
                hhi[(size_t)node * D + f] = sh;
                hlo[(size_t)node * D + f] = sl;
            }
        }
    }
}

// ---------------------------------------------------------------------------
extern "C" void kernel_launch(void* const* d_in, const int* in_sizes, int n_in,
                              void* d_out, int out_size, void* d_ws, size_t ws_size,
                              hipStream_t stream) {
    const int* x      = (const int*)d_in[0];
    const int* ei     = (const int*)d_in[1];
    const int* et     = (const int*)d_in[2];
    const int* nt     = (const int*)d_in[3];
    const float* emb  = (const float*)d_in[4];
    const float* Wrel = (const float*)d_in[5];
    const float* b_node = (const float*)d_in[6];
    const float* W_ih = (const float*)d_in[7];
    const float* W_hh = (const float*)d_in[8];
    const float* b_ih = (const float*)d_in[9];
    const float* b_hh = (const float*)d_in[10];

    float* h = (float*)d_out;
    float* ws = (float*)d_ws;

    // workspace layout (total 157.9 MB, well under proven >=234 MB)
    ushort_t* Ht = (ushort_t*)ws;                          // 51,200,000 us (fp16)
    ushort_t* us = (ushort_t*)(ws + 25600000);
    ushort_t* ahi  = us;                                   // 6,400,000 each
    ushort_t* alo  = us + 6400000;
    ushort_t* hhi  = us + 12800000;
    ushort_t* hlo  = us + 19200000;
    ushort_t* Whi  = us + 25600000;                        //   131,072 each
    ushort_t* Wlo  = Whi + 131072;
    ushort_t* Wihi = Wlo + 131072;                         //    49,152 each
    ushort_t* Wilo = Wihi + 49152;
    ushort_t* Whhi = Wilo + 49152;
    ushort_t* Whlo = Whhi + 49152;
    int* rs     = (int*)(ws + 38629376);                   //    50,004
    int* packed = rs + 50004;                              //   800,000
    int* deg    = (int*)ws;                                // transient alias in Ht region (pre-loop only)

    convert_wrelT<<<512, 256, 0, stream>>>(Wrel, Whi, Wlo);
    convert_w<<<192, 256, 0, stream>>>(W_ih, Wihi, Wilo, 3 * D * D);
    convert_w<<<192, 256, 0, stream>>>(W_hh, Whhi, Whlo, 3 * D * D);
    embed_gather<<<N_NODES, 128, 0, stream>>>(x, emb, h, hhi, hlo);

    hipMemsetAsync(deg, 0, 50000 * sizeof(int), stream);
    count_deg<<<3125, 256, 0, stream>>>(ei, deg);
    scan_deg<<<1, 1024, 0, stream>>>(deg, rs, deg);   // cursor aliases deg
    fill_csr<<<3125, 256, 0, stream>>>(ei, et, deg, packed);

    for (int it = 0; it < 5; ++it) {
        dim3 g(782, T_TYPES);
        gemm_rel<<<g, 256, 0, stream>>>(hhi, hlo, Whi, Wlo, Ht);
        aggregate_csr<<<12500, 256, 0, stream>>>(rs, packed, Ht, nt, b_node, ahi, alo);
        gru_mfma<<<782, 512, 0, stream>>>(ahi, alo, hhi, hlo,
                                          Wihi, Wilo, Whhi, Whlo, b_ih, b_hh, h);
    }
}

// Round 8
// 1206.524 us; speedup vs baseline: 2.2341x; 1.7581x over previous
//
#include <hip/hip_runtime.h>
#include <hip/hip_fp16.h>
#include <math.h>

#define N_NODES 50000
#define N_EDGES 800000
#define D 128
#define T_TYPES 8
#define TPAD 136   // padded LDS row stride (ushorts): 68 dwords -> row shifts 4 banks; 2-way max (free)

typedef short short8 __attribute__((ext_vector_type(8)));
typedef float float4v __attribute__((ext_vector_type(4)));
typedef unsigned short ushort_t;

static __device__ __forceinline__ unsigned short f2bf(float f) {
    unsigned u = __float_as_uint(f);
    u += 0x7fff + ((u >> 16) & 1);   // round-to-nearest-even
    return (unsigned short)(u >> 16);
}
static __device__ __forceinline__ float bf2f(unsigned short b) {
    return __uint_as_float((unsigned)b << 16);
}
// exact two-term split: x ~= hi + lo, error <= 2^-18 |x|
static __device__ __forceinline__ void splitbf(float x, unsigned short& hi, unsigned short& lo) {
    unsigned short h_ = f2bf(x);
    hi = h_;
    lo = f2bf(x - bf2f(h_));
}

// ---------------------------------------------------------------------------
__global__ void embed_gather(const int* __restrict__ x, const float* __restrict__ emb,
                             float* __restrict__ h,
                             ushort_t* __restrict__ hhi, ushort_t* __restrict__ hlo) {
    int n = blockIdx.x;
    int d = threadIdx.x;
    float v = emb[(size_t)x[n] * D + d];
    h[(size_t)n * D + d] = v;
    unsigned short a, b;
    splitbf(v, a, b);
    hhi[(size_t)n * D + d] = a;
    hlo[(size_t)n * D + d] = b;
}

// WrelT[t][f][d] = Wrel[t][d][f], split hi/lo bf16
__global__ void convert_wrelT(const float* __restrict__ Wrel,
                              ushort_t* __restrict__ hi, ushort_t* __restrict__ lo) {
    int idx = blockIdx.x * 256 + threadIdx.x; // 0..131071
    int t = idx >> 14;
    int rem = idx & 16383;
    int f = rem >> 7;
    int d = rem & 127;
    unsigned short a, b;
    splitbf(Wrel[((size_t)t << 14) + (d << 7) + f], a, b);
    hi[idx] = a;
    lo[idx] = b;
}

// GRU weights keep [3D][D] layout (already B^T form), split hi/lo
__global__ void convert_w(const float* __restrict__ in,
                          ushort_t* __restrict__ hi, ushort_t* __restrict__ lo, int n) {
    int idx = blockIdx.x * 256 + threadIdx.x;
    if (idx < n) {
        unsigned short a, b;
        splitbf(in[idx], a, b);
        hi[idx] = a;
        lo[idx] = b;
    }
}

// ---------------------------------------------------------------------------
// CSR build over dst
__global__ void count_deg(const int* __restrict__ ei, int* __restrict__ deg) {
    int e = blockIdx.x * 256 + threadIdx.x;
    if (e >= N_EDGES) return;
    atomicAdd(&deg[ei[N_EDGES + e]], 1);
}

__global__ __launch_bounds__(1024) void scan_deg(const int* __restrict__ deg,
                                                 int* __restrict__ rs,
                                                 int* __restrict__ cursor) {
    __shared__ int sums[1024];
    const int tid = threadIdx.x;
    const int CH = 49;
    const int base = tid * CH;
    int s = 0;
    for (int i = 0; i < CH; ++i) {
        int idx = base + i;
        if (idx < N_NODES) s += deg[idx];
    }
    sums[tid] = s;
    __syncthreads();
    for (int ofs = 1; ofs < 1024; ofs <<= 1) {
        int v = (tid >= ofs) ? sums[tid - ofs] : 0;
        __syncthreads();
        sums[tid] += v;
        __syncthreads();
    }
    int run = sums[tid] - s;
    for (int i = 0; i < CH; ++i) {
        int idx = base + i;
        if (idx < N_NODES) {
            int dv = deg[idx];      // read BEFORE cursor write (cursor aliases deg)
            rs[idx] = run;
            cursor[idx] = run;
            run += dv;
        }
    }
    if (tid == 0) rs[N_NODES] = N_EDGES;
}

__global__ void fill_csr(const int* __restrict__ ei, const int* __restrict__ et,
                         int* __restrict__ cursor, int* __restrict__ packed) {
    int e = blockIdx.x * 256 + threadIdx.x;
    if (e >= N_EDGES) return;
    int dst = ei[N_EDGES + e];
    int pos = atomicAdd(&cursor[dst], 1);
    packed[pos] = (ei[e] << 3) | et[e];
}

// ---------------------------------------------------------------------------
// Relational transform, bf16x3 MFMA. Weights staged in LDS (shared by 4 waves,
// read via ds_read_b128 ~12cyc instead of per-wave serialized L2 loads ~200cyc —
// R6/R7 showed 21K cyc/wave with all pipes <8% from exactly that).
// Block 256 thr = 4 waves; block tile 128 rows x 128 cols (one type).
// Wave: 32 rows (2 m-subtiles) -> each B-frag ds_read feeds 6 MFMAs.
__global__ __launch_bounds__(256, 2) void gemm_rel(const ushort_t* __restrict__ hhi,
                                                   const ushort_t* __restrict__ hlo,
                                                   const ushort_t* __restrict__ Whi,
                                                   const ushort_t* __restrict__ Wlo,
                                                   ushort_t* __restrict__ Ht) {
    __shared__ __align__(16) ushort_t wlds[2][128 * TPAD];  // hi/lo planes, 69632 B
    const int tid = threadIdx.x;
    const int wave = tid >> 6, lane = tid & 63;
    const int q = lane >> 4, li = lane & 15;
    const int t = blockIdx.y;
    const int m_base = blockIdx.x * 128 + wave * 32;

    // ---- stage weights (each plane 16384 ushorts; 256 thr x 8 x short8) ----
    {
        const ushort_t* gh = Whi + ((size_t)t << 14);
        const ushort_t* gl = Wlo + ((size_t)t << 14);
#pragma unroll
        for (int i = 0; i < 8; ++i) {
            int g = (i * 256 + tid) * 8;         // 0..16376
            int row = g >> 7, col = g & 127;
            *(short8*)(&wlds[0][row * TPAD + col]) = *(const short8*)(gh + g);
            *(short8*)(&wlds[1][row * TPAD + col]) = *(const short8*)(gl + g);
        }
    }
    __syncthreads();

    // ---- A fragments: 2 row-subtiles, preloaded as one batch of 16 loads ----
    int r0 = m_base + li;      if (r0 > N_NODES - 1) r0 = N_NODES - 1;
    int r1 = m_base + 16 + li; if (r1 > N_NODES - 1) r1 = N_NODES - 1;
    const ushort_t* A0h = hhi + (size_t)r0 * D + q * 8;
    const ushort_t* A0l = hlo + (size_t)r0 * D + q * 8;
    const ushort_t* A1h = hhi + (size_t)r1 * D + q * 8;
    const ushort_t* A1l = hlo + (size_t)r1 * D + q * 8;

    short8 a0h[4], a0l[4], a1h[4], a1l[4];
#pragma unroll
    for (int ks = 0; ks < 4; ++ks) {
        a0h[ks] = *(const short8*)(A0h + ks * 32);
        a0l[ks] = *(const short8*)(A0l + ks * 32);
        a1h[ks] = *(const short8*)(A1h + ks * 32);
        a1l[ks] = *(const short8*)(A1l + ks * 32);
    }

    float4v acc[2][8];
#pragma unroll
    for (int m = 0; m < 2; ++m)
#pragma unroll
        for (int ft = 0; ft < 8; ++ft) acc[m][ft] = (float4v){0.f, 0.f, 0.f, 0.f};

#pragma unroll
    for (int ks = 0; ks < 4; ++ks) {
#pragma unroll
        for (int ft = 0; ft < 8; ++ft) {
            const int lo_off = (ft * 16 + li) * TPAD + ks * 32 + q * 8;
            short8 bh = *(const short8*)(&wlds[0][lo_off]);
            short8 bl = *(const short8*)(&wlds[1][lo_off]);
            acc[0][ft] = __builtin_amdgcn_mfma_f32_16x16x32_bf16(a0h[ks], bh, acc[0][ft], 0, 0, 0);
            acc[0][ft] = __builtin_amdgcn_mfma_f32_16x16x32_bf16(a0l[ks], bh, acc[0][ft], 0, 0, 0);
            acc[0][ft] = __builtin_amdgcn_mfma_f32_16x16x32_bf16(a0h[ks], bl, acc[0][ft], 0, 0, 0);
            acc[1][ft] = __builtin_amdgcn_mfma_f32_16x16x32_bf16(a1h[ks], bh, acc[1][ft], 0, 0, 0);
            acc[1][ft] = __builtin_amdgcn_mfma_f32_16x16x32_bf16(a1l[ks], bh, acc[1][ft], 0, 0, 0);
            acc[1][ft] = __builtin_amdgcn_mfma_f32_16x16x32_bf16(a1h[ks], bl, acc[1][ft], 0, 0, 0);
        }
    }

    __syncthreads();   // all weight ds_reads done -> reuse LDS for epilogue
    // wave-private 32x128 fp16 out tile
    ushort_t* tw = &wlds[0][0] + wave * 32 * TPAD;   // 8704 B/wave, 4 waves fit plane0+
#pragma unroll
    for (int m = 0; m < 2; ++m)
#pragma unroll
        for (int ft = 0; ft < 8; ++ft)
#pragma unroll
            for (int r = 0; r < 4; ++r) {
                __half hv = __float2half_rn(acc[m][ft][r]);
                tw[(m * 16 + q * 4 + r) * TPAD + ft * 16 + li] = __half_as_ushort(hv);
            }
    // wave-local LDS round-trip: compiler's lgkmcnt ordering suffices
#pragma unroll
    for (int i = 0; i < 8; ++i) {
        int row = i * 4 + q;       // 0..31
        int col = li * 8;
        short8 v = *(const short8*)(tw + row * TPAD + col);
        int orow = m_base + row;
        if (orow < N_NODES)
            *(short8*)(Ht + (size_t)orow * 1024 + (t << 7) + col) = v;
    }
}

// ---------------------------------------------------------------------------
// CSR aggregation: one wave per dst node; fp16 Ht gather, fp32 accumulate,
// pre-split bf16 hi/lo output. Fuses b_node bias.
__global__ __launch_bounds__(256) void aggregate_csr(const int* __restrict__ rs,
                                                     const int* __restrict__ packed,
                                                     const ushort_t* __restrict__ Ht,
                                                     const int* __restrict__ nt,
                                                     const float* __restrict__ b_node,
                                                     ushort_t* __restrict__ ahi,
                                                     ushort_t* __restrict__ alo) {
    int n = blockIdx.x * 4 + (threadIdx.x >> 6);
    if (n >= N_NODES) return;
    const int lane = threadIdx.x & 63;
    const int beg = rs[n], end = rs[n + 1];
    const __half2* Ht2 = (const __half2*)Ht;

    float2 acc = ((const float2*)(b_node + (size_t)nt[n] * D))[lane];

    int i = beg;
    for (; i + 3 < end; i += 4) {
        int p0 = packed[i], p1 = packed[i + 1], p2 = packed[i + 2], p3 = packed[i + 3];
        float2 f0 = __half22float2(Ht2[(size_t)p0 * 64 + lane]);
        float2 f1 = __half22float2(Ht2[(size_t)p1 * 64 + lane]);
        float2 f2 = __half22float2(Ht2[(size_t)p2 * 64 + lane]);
        float2 f3 = __half22float2(Ht2[(size_t)p3 * 64 + lane]);
        acc.x += (f0.x + f1.x) + (f2.x + f3.x);
        acc.y += (f0.y + f1.y) + (f2.y + f3.y);
    }
    for (; i < end; ++i) {
        int pk = packed[i];
        float2 fv = __half22float2(Ht2[(size_t)pk * 64 + lane]);
        acc.x += fv.x;
        acc.y += fv.y;
    }

    unsigned short h0, l0, h1, l1;
    splitbf(acc.x, h0, l0);
    splitbf(acc.y, h1, l1);
    ((unsigned*)ahi)[(size_t)n * 64 + lane] = (unsigned)h0 | ((unsigned)h1 << 16);
    ((unsigned*)alo)[(size_t)n * 64 + lane] = (unsigned)l0 | ((unsigned)l1 << 16);
}

// ---------------------------------------------------------------------------
// Fused GRU, bf16x3 MFMA. Block = 512 thr = 8 waves, 64 rows x 128 cols.
// x-state (ahi/alo/hhi/hlo) staged in LDS once — all 8 waves read the SAME rows,
// previously 8x duplicated serialized global loads. Weight frags stay global (L2).
__global__ __launch_bounds__(512, 2) void gru_mfma(const ushort_t* __restrict__ ahi,
                                                   const ushort_t* __restrict__ alo,
                                                   ushort_t* __restrict__ hhi,
                                                   ushort_t* __restrict__ hlo,
                                                   const ushort_t* __restrict__ Wihi,
                                                   const ushort_t* __restrict__ Wilo,
                                                   const ushort_t* __restrict__ Whhi,
                                                   const ushort_t* __restrict__ Whlo,
                                                   const float* __restrict__ b_ih,
                                                   const float* __restrict__ b_hh,
                                                   float* __restrict__ h) {
    __shared__ __align__(16) ushort_t xlds[4][64 * TPAD];  // 69632 B
    const int tid = threadIdx.x;
    const int wave = tid >> 6, lane = tid & 63;
    const int q = lane >> 4, li = lane & 15;
    const int n0 = blockIdx.x * 64;
    const int f = wave * 16 + li;

    // ---- stage x-state: 4 arrays x 8192 ushorts; 512 thr x 2 x short8 each ----
#pragma unroll
    for (int i = 0; i < 2; ++i) {
        int g = (i * 512 + tid) * 8;   // 0..8184
        int row = g >> 7, col = g & 127;
        int gr = n0 + row;
        if (gr > N_NODES - 1) gr = N_NODES - 1;
        size_t go = (size_t)gr * D + col;
        int la = row * TPAD + col;
        *(short8*)(&xlds[0][la]) = *(const short8*)(ahi + go);
        *(short8*)(&xlds[1][la]) = *(const short8*)(alo + go);
        *(short8*)(&xlds[2][la]) = *(const short8*)(hhi + go);
        *(short8*)(&xlds[3][la]) = *(const short8*)(hlo + go);
    }
    __syncthreads();

    const size_t oR = (size_t)f * D + q * 8;
    const size_t oZ = (size_t)(D + f) * D + q * 8;
    const size_t oN = (size_t)(2 * D + f) * D + q * 8;

    float4v aR[4], aZ[4], aI[4], aH[4];
#pragma unroll
    for (int m = 0; m < 4; ++m) {
        aR[m] = (float4v){0.f, 0.f, 0.f, 0.f};
        aZ[m] = aR[m]; aI[m] = aR[m]; aH[m] = aR[m];
    }

#pragma unroll
    for (int ks = 0; ks < 4; ++ks) {
        const int off = ks * 32;
        short8 wIRh = *(const short8*)(Wihi + oR + off);
        short8 wIRl = *(const short8*)(Wilo + oR + off);
        short8 wHRh = *(const short8*)(Whhi + oR + off);
        short8 wHRl = *(const short8*)(Whlo + oR + off);
        short8 wIZh = *(const short8*)(Wihi + oZ + off);
        short8 wIZl = *(const short8*)(Wilo + oZ + off);
        short8 wHZh = *(const short8*)(Whhi + oZ + off);
        short8 wHZl = *(const short8*)(Whlo + oZ + off);
        short8 wINh = *(const short8*)(Wihi + oN + off);
        short8 wINl = *(const short8*)(Wilo + oN + off);
        short8 wHNh = *(const short8*)(Whhi + oN + off);
        short8 wHNl = *(const short8*)(Whlo + oN + off);
#pragma unroll
        for (int m = 0; m < 4; ++m) {
            const int lo_off = (m * 16 + li) * TPAD + off + q * 8;
            short8 xah = *(const short8*)(&xlds[0][lo_off]);
            short8 xal = *(const short8*)(&xlds[1][lo_off]);
            short8 xhh = *(const short8*)(&xlds[2][lo_off]);
            short8 xhl = *(const short8*)(&xlds[3][lo_off]);
            aR[m] = __builtin_amdgcn_mfma_f32_16x16x32_bf16(xah, wIRh, aR[m], 0, 0, 0);
            aR[m] = __builtin_amdgcn_mfma_f32_16x16x32_bf16(xal, wIRh, aR[m], 0, 0, 0);
            aR[m] = __builtin_amdgcn_mfma_f32_16x16x32_bf16(xah, wIRl, aR[m], 0, 0, 0);
            aR[m] = __builtin_amdgcn_mfma_f32_16x16x32_bf16(xhh, wHRh, aR[m], 0, 0, 0);
            aR[m] = __builtin_amdgcn_mfma_f32_16x16x32_bf16(xhl, wHRh, aR[m], 0, 0, 0);
            aR[m] = __builtin_amdgcn_mfma_f32_16x16x32_bf16(xhh, wHRl, aR[m], 0, 0, 0);
            aZ[m] = __builtin_amdgcn_mfma_f32_16x16x32_bf16(xah, wIZh, aZ[m], 0, 0, 0);
            aZ[m] = __builtin_amdgcn_mfma_f32_16x16x32_bf16(xal, wIZh, aZ[m], 0, 0, 0);
            aZ[m] = __builtin_amdgcn_mfma_f32_16x16x32_bf16(xah, wIZl, aZ[m], 0, 0, 0);
            aZ[m] = __builtin_amdgcn_mfma_f32_16x16x32_bf16(xhh, wHZh, aZ[m], 0, 0, 0);
            aZ[m] = __builtin_amdgcn_mfma_f32_16x16x32_bf16(xhl, wHZh, aZ[m], 0, 0, 0);
            aZ[m] = __builtin_amdgcn_mfma_f32_16x16x32_bf16(xhh, wHZl, aZ[m], 0, 0, 0);
            aI[m] = __builtin_amdgcn_mfma_f32_16x16x32_bf16(xah, wINh, aI[m], 0, 0, 0);
            aI[m] = __builtin_amdgcn_mfma_f32_16x16x32_bf16(xal, wINh, aI[m], 0, 0, 0);
            aI[m] = __builtin_amdgcn_mfma_f32_16x16x32_bf16(xah, wINl, aI[m], 0, 0, 0);
            aH[m] = __builtin_amdgcn_mfma_f32_16x16x32_bf16(xhh, wHNh, aH[m], 0, 0, 0);
            aH[m] = __builtin_amdgcn_mfma_f32_16x16x32_bf16(xhl, wHNh, aH[m], 0, 0, 0);
            aH[m] = __builtin_amdgcn_mfma_f32_16x16x32_bf16(xhh, wHNl, aH[m], 0, 0, 0);
        }
    }

    const float bR = b_ih[f] + b_hh[f];
    const float bZ = b_ih[D + f] + b_hh[D + f];
    const float bIn = b_ih[2 * D + f];
    const float bHn = b_hh[2 * D + f];

    // hold reads are (node,f)-exclusive to this lane; x reads came from LDS,
    // so no barrier needed before in-place writes (rows are block-exclusive).
#pragma unroll
    for (int m = 0; m < 4; ++m) {
#pragma unroll
        for (int r = 0; r < 4; ++r) {
            int node = n0 + m * 16 + q * 4 + r;
            if (node < N_NODES) {
                float hold = h[(size_t)node * D + f];
                float rg = 1.0f / (1.0f + __expf(-(aR[m][r] + bR)));
                float zg = 1.0f / (1.0f + __expf(-(aZ[m][r] + bZ)));
                float narg = aI[m][r] + bIn + rg * (aH[m][r] + bHn);
                float ex = __expf(2.0f * narg);
                float ng = 1.0f - 2.0f / (ex + 1.0f);   // tanh
                float hn = (1.0f - zg) * ng + zg * hold;
                h[(size_t)node * D + f] = hn;
                unsigned short sh, sl;
                splitbf(hn, sh, sl);
                hhi[(size_t)node * D + f] = sh;
                hlo[(size_t)node * D + f] = sl;
            }
        }
    }
}

// ---------------------------------------------------------------------------
extern "C" void kernel_launch(void* const* d_in, const int* in_sizes, int n_in,
                              void* d_out, int out_size, void* d_ws, size_t ws_size,
                              hipStream_t stream) {
    const int* x      = (const int*)d_in[0];
    const int* ei     = (const int*)d_in[1];
    const int* et     = (const int*)d_in[2];
    const int* nt     = (const int*)d_in[3];
    const float* emb  = (const float*)d_in[4];
    const float* Wrel = (const float*)d_in[5];
    const float* b_node = (const float*)d_in[6];
    const float* W_ih = (const float*)d_in[7];
    const float* W_hh = (const float*)d_in[8];
    const float* b_ih = (const float*)d_in[9];
    const float* b_hh = (const float*)d_in[10];

    float* h = (float*)d_out;
    float* ws = (float*)d_ws;

    // workspace layout (total 157.9 MB, well under proven >=234 MB)
    ushort_t* Ht = (ushort_t*)ws;                          // 51,200,000 us (fp16)
    ushort_t* us = (ushort_t*)(ws + 25600000);
    ushort_t* ahi  = us;                                   // 6,400,000 each
    ushort_t* alo  = us + 6400000;
    ushort_t* hhi  = us + 12800000;
    ushort_t* hlo  = us + 19200000;
    ushort_t* Whi  = us + 25600000;                        //   131,072 each
    ushort_t* Wlo  = Whi + 131072;
    ushort_t* Wihi = Wlo + 131072;                         //    49,152 each
    ushort_t* Wilo = Wihi + 49152;
    ushort_t* Whhi = Wilo + 49152;
    ushort_t* Whlo = Whhi + 49152;
    int* rs     = (int*)(ws + 38629376);                   //    50,004
    int* packed = rs + 50004;                              //   800,000
    int* deg    = (int*)ws;                                // transient alias in Ht region (pre-loop only)

    convert_wrelT<<<512, 256, 0, stream>>>(Wrel, Whi, Wlo);
    convert_w<<<192, 256, 0, stream>>>(W_ih, Wihi, Wilo, 3 * D * D);
    convert_w<<<192, 256, 0, stream>>>(W_hh, Whhi, Whlo, 3 * D * D);
    embed_gather<<<N_NODES, 128, 0, stream>>>(x, emb, h, hhi, hlo);

    hipMemsetAsync(deg, 0, 50000 * sizeof(int), stream);
    count_deg<<<3125, 256, 0, stream>>>(ei, deg);
    scan_deg<<<1, 1024, 0, stream>>>(deg, rs, deg);   // cursor aliases deg
    fill_csr<<<3125, 256, 0, stream>>>(ei, et, deg, packed);

    for (int it = 0; it < 5; ++it) {
        dim3 g(391, T_TYPES);   // 391*128 = 50048 rows
        gemm_rel<<<g, 256, 0, stream>>>(hhi, hlo, Whi, Wlo, Ht);
        aggregate_csr<<<12500, 256, 0, stream>>>(rs, packed, Ht, nt, b_node, ahi, alo);
        gru_mfma<<<782, 512, 0, stream>>>(ahi, alo, hhi, hlo,
                                          Wihi, Wilo, Whhi, Whlo, b_ih, b_hh, h);
    }
}

// Round 9
// 1079.380 us; speedup vs baseline: 2.4973x; 1.1178x over previous
//
#include <hip/hip_runtime.h>
#include <hip/hip_fp16.h>
#include <math.h>

#define N_NODES 50000
#define N_EDGES 800000
#define D 128
#define T_TYPES 8
#define TPAD 136   // padded LDS row stride (ushorts): 68 dwords -> row shifts 4 banks; 2-way max (free)
#define NBLK_SCAN 196   // ceil(50000/256)

typedef short short8 __attribute__((ext_vector_type(8)));
typedef float float4v __attribute__((ext_vector_type(4)));
typedef unsigned short ushort_t;

static __device__ __forceinline__ unsigned short f2bf(float f) {
    unsigned u = __float_as_uint(f);
    u += 0x7fff + ((u >> 16) & 1);   // round-to-nearest-even
    return (unsigned short)(u >> 16);
}
static __device__ __forceinline__ float bf2f(unsigned short b) {
    return __uint_as_float((unsigned)b << 16);
}
// exact two-term split: x ~= hi + lo, error <= 2^-18 |x|
static __device__ __forceinline__ void splitbf(float x, unsigned short& hi, unsigned short& lo) {
    unsigned short h_ = f2bf(x);
    hi = h_;
    lo = f2bf(x - bf2f(h_));
}

// ---------------------------------------------------------------------------
__global__ void embed_gather(const int* __restrict__ x, const float* __restrict__ emb,
                             float* __restrict__ h,
                             ushort_t* __restrict__ hhi, ushort_t* __restrict__ hlo) {
    int n = blockIdx.x;
    int d = threadIdx.x;
    float v = emb[(size_t)x[n] * D + d];
    h[(size_t)n * D + d] = v;
    unsigned short a, b;
    splitbf(v, a, b);
    hhi[(size_t)n * D + d] = a;
    hlo[(size_t)n * D + d] = b;
}

// WrelT[t][f][d] = Wrel[t][d][f], split hi/lo bf16
__global__ void convert_wrelT(const float* __restrict__ Wrel,
                              ushort_t* __restrict__ hi, ushort_t* __restrict__ lo) {
    int idx = blockIdx.x * 256 + threadIdx.x; // 0..131071
    int t = idx >> 14;
    int rem = idx & 16383;
    int f = rem >> 7;
    int d = rem & 127;
    unsigned short a, b;
    splitbf(Wrel[((size_t)t << 14) + (d << 7) + f], a, b);
    hi[idx] = a;
    lo[idx] = b;
}

// GRU weights keep [3D][D] layout (already B^T form), split hi/lo
__global__ void convert_w(const float* __restrict__ in,
                          ushort_t* __restrict__ hi, ushort_t* __restrict__ lo, int n) {
    int idx = blockIdx.x * 256 + threadIdx.x;
    if (idx < n) {
        unsigned short a, b;
        splitbf(in[idx], a, b);
        hi[idx] = a;
        lo[idx] = b;
    }
}

// ---------------------------------------------------------------------------
// CSR build over dst
__global__ void count_deg(const int* __restrict__ ei, int* __restrict__ deg) {
    int e = blockIdx.x * 256 + threadIdx.x;
    if (e >= N_EDGES) return;
    atomicAdd(&deg[ei[N_EDGES + e]], 1);
}

// Two-level scan replacing the single-block scan_deg (R8: 127us on one CU —
// 10% of total runtime, 0.05% HBM util). Three tiny kernels, ~10us total.
__global__ __launch_bounds__(256) void scan_blocks(const int* __restrict__ deg,
                                                   int* __restrict__ bsums) {
    __shared__ int red[4];
    int idx = blockIdx.x * 256 + threadIdx.x;
    int v = (idx < N_NODES) ? deg[idx] : 0;
#pragma unroll
    for (int o = 32; o > 0; o >>= 1) v += __shfl_down(v, o);
    if ((threadIdx.x & 63) == 0) red[threadIdx.x >> 6] = v;
    __syncthreads();
    if (threadIdx.x == 0) bsums[blockIdx.x] = red[0] + red[1] + red[2] + red[3];
}

__global__ __launch_bounds__(256) void scan_tops(int* __restrict__ bsums) {
    __shared__ int s[256];
    int tid = threadIdx.x;
    int v = (tid < NBLK_SCAN) ? bsums[tid] : 0;
    s[tid] = v;
    __syncthreads();
#pragma unroll
    for (int o = 1; o < 256; o <<= 1) {
        int u = (tid >= o) ? s[tid - o] : 0;
        __syncthreads();
        s[tid] += u;
        __syncthreads();
    }
    if (tid < NBLK_SCAN) bsums[tid] = s[tid] - v;   // exclusive
}

// reads deg, writes rs + cursor. cursor may alias deg: each index is read and
// written only by its owning thread, read precedes write in program order.
__global__ __launch_bounds__(256) void scan_final(const int* __restrict__ bsums,
                                                  int* __restrict__ deg_cursor,
                                                  int* __restrict__ rs) {
    __shared__ int s[256];
    int tid = threadIdx.x;
    int idx = blockIdx.x * 256 + tid;
    int v = (idx < N_NODES) ? deg_cursor[idx] : 0;
    s[tid] = v;
    __syncthreads();
#pragma unroll
    for (int o = 1; o < 256; o <<= 1) {
        int u = (tid >= o) ? s[tid - o] : 0;
        __syncthreads();
        s[tid] += u;
        __syncthreads();
    }
    int excl = s[tid] - v + bsums[blockIdx.x];
    if (idx < N_NODES) {
        rs[idx] = excl;
        deg_cursor[idx] = excl;
    }
    if (idx == 0) rs[N_NODES] = N_EDGES;
}

__global__ void fill_csr(const int* __restrict__ ei, const int* __restrict__ et,
                         int* __restrict__ cursor, int* __restrict__ packed) {
    int e = blockIdx.x * 256 + threadIdx.x;
    if (e >= N_EDGES) return;
    int dst = ei[N_EDGES + e];
    int pos = atomicAdd(&cursor[dst], 1);
    packed[pos] = (ei[e] << 3) | et[e];
}

// ---------------------------------------------------------------------------
// Relational transform, bf16x3 MFMA. Weights staged in LDS (shared by 4 waves).
// Block 256 thr = 4 waves; block tile 128 rows x 128 cols (one type).
// Wave: 32 rows (2 m-subtiles) -> each B-frag ds_read feeds 6 MFMAs.
__global__ __launch_bounds__(256, 2) void gemm_rel(const ushort_t* __restrict__ hhi,
                                                   const ushort_t* __restrict__ hlo,
                                                   const ushort_t* __restrict__ Whi,
                                                   const ushort_t* __restrict__ Wlo,
                                                   ushort_t* __restrict__ Ht) {
    __shared__ __align__(16) ushort_t wlds[2][128 * TPAD];  // hi/lo planes, 69632 B
    const int tid = threadIdx.x;
    const int wave = tid >> 6, lane = tid & 63;
    const int q = lane >> 4, li = lane & 15;
    const int t = blockIdx.y;
    const int m_base = blockIdx.x * 128 + wave * 32;

    // ---- stage weights (each plane 16384 ushorts; 256 thr x 8 x short8) ----
    {
        const ushort_t* gh = Whi + ((size_t)t << 14);
        const ushort_t* gl = Wlo + ((size_t)t << 14);
#pragma unroll
        for (int i = 0; i < 8; ++i) {
            int g = (i * 256 + tid) * 8;         // 0..16376
            int row = g >> 7, col = g & 127;
            *(short8*)(&wlds[0][row * TPAD + col]) = *(const short8*)(gh + g);
            *(short8*)(&wlds[1][row * TPAD + col]) = *(const short8*)(gl + g);
        }
    }
    __syncthreads();

    // ---- A fragments: 2 row-subtiles, preloaded as one batch of 16 loads ----
    int r0 = m_base + li;      if (r0 > N_NODES - 1) r0 = N_NODES - 1;
    int r1 = m_base + 16 + li; if (r1 > N_NODES - 1) r1 = N_NODES - 1;
    const ushort_t* A0h = hhi + (size_t)r0 * D + q * 8;
    const ushort_t* A0l = hlo + (size_t)r0 * D + q * 8;
    const ushort_t* A1h = hhi + (size_t)r1 * D + q * 8;
    const ushort_t* A1l = hlo + (size_t)r1 * D + q * 8;

    short8 a0h[4], a0l[4], a1h[4], a1l[4];
#pragma unroll
    for (int ks = 0; ks < 4; ++ks) {
        a0h[ks] = *(const short8*)(A0h + ks * 32);
        a0l[ks] = *(const short8*)(A0l + ks * 32);
        a1h[ks] = *(const short8*)(A1h + ks * 32);
        a1l[ks] = *(const short8*)(A1l + ks * 32);
    }

    float4v acc[2][8];
#pragma unroll
    for (int m = 0; m < 2; ++m)
#pragma unroll
        for (int ft = 0; ft < 8; ++ft) acc[m][ft] = (float4v){0.f, 0.f, 0.f, 0.f};

#pragma unroll
    for (int ks = 0; ks < 4; ++ks) {
#pragma unroll
        for (int ft = 0; ft < 8; ++ft) {
            const int lo_off = (ft * 16 + li) * TPAD + ks * 32 + q * 8;
            short8 bh = *(const short8*)(&wlds[0][lo_off]);
            short8 bl = *(const short8*)(&wlds[1][lo_off]);
            acc[0][ft] = __builtin_amdgcn_mfma_f32_16x16x32_bf16(a0h[ks], bh, acc[0][ft], 0, 0, 0);
            acc[0][ft] = __builtin_amdgcn_mfma_f32_16x16x32_bf16(a0l[ks], bh, acc[0][ft], 0, 0, 0);
            acc[0][ft] = __builtin_amdgcn_mfma_f32_16x16x32_bf16(a0h[ks], bl, acc[0][ft], 0, 0, 0);
            acc[1][ft] = __builtin_amdgcn_mfma_f32_16x16x32_bf16(a1h[ks], bh, acc[1][ft], 0, 0, 0);
            acc[1][ft] = __builtin_amdgcn_mfma_f32_16x16x32_bf16(a1l[ks], bh, acc[1][ft], 0, 0, 0);
            acc[1][ft] = __builtin_amdgcn_mfma_f32_16x16x32_bf16(a1h[ks], bl, acc[1][ft], 0, 0, 0);
        }
    }

    __syncthreads();   // all weight ds_reads done -> reuse LDS for epilogue
    // wave-private 32x128 fp16 out tile
    ushort_t* tw = &wlds[0][0] + wave * 32 * TPAD;
#pragma unroll
    for (int m = 0; m < 2; ++m)
#pragma unroll
        for (int ft = 0; ft < 8; ++ft)
#pragma unroll
            for (int r = 0; r < 4; ++r) {
                __half hv = __float2half_rn(acc[m][ft][r]);
                tw[(m * 16 + q * 4 + r) * TPAD + ft * 16 + li] = __half_as_ushort(hv);
            }
    // wave-local LDS round-trip: compiler's lgkmcnt ordering suffices
#pragma unroll
    for (int i = 0; i < 8; ++i) {
        int row = i * 4 + q;       // 0..31
        int col = li * 8;
        short8 v = *(const short8*)(tw + row * TPAD + col);
        int orow = m_base + row;
        if (orow < N_NODES)
            *(short8*)(Ht + (size_t)orow * 1024 + (t << 7) + col) = v;
    }
}

// ---------------------------------------------------------------------------
// CSR aggregation: one wave per dst node; fp16 Ht gather, fp32 accumulate,
// pre-split bf16 hi/lo output. Fuses b_node bias.
__global__ __launch_bounds__(256) void aggregate_csr(const int* __restrict__ rs,
                                                     const int* __restrict__ packed,
                                                     const ushort_t* __restrict__ Ht,
                                                     const int* __restrict__ nt,
                                                     const float* __restrict__ b_node,
                                                     ushort_t* __restrict__ ahi,
                                                     ushort_t* __restrict__ alo) {
    int n = blockIdx.x * 4 + (threadIdx.x >> 6);
    if (n >= N_NODES) return;
    const int lane = threadIdx.x & 63;
    const int beg = rs[n], end = rs[n + 1];
    const __half2* Ht2 = (const __half2*)Ht;

    float2 acc = ((const float2*)(b_node + (size_t)nt[n] * D))[lane];

    int i = beg;
    for (; i + 3 < end; i += 4) {
        int p0 = packed[i], p1 = packed[i + 1], p2 = packed[i + 2], p3 = packed[i + 3];
        float2 f0 = __half22float2(Ht2[(size_t)p0 * 64 + lane]);
        float2 f1 = __half22float2(Ht2[(size_t)p1 * 64 + lane]);
        float2 f2 = __half22float2(Ht2[(size_t)p2 * 64 + lane]);
        float2 f3 = __half22float2(Ht2[(size_t)p3 * 64 + lane]);
        acc.x += (f0.x + f1.x) + (f2.x + f3.x);
        acc.y += (f0.y + f1.y) + (f2.y + f3.y);
    }
    for (; i < end; ++i) {
        int pk = packed[i];
        float2 fv = __half22float2(Ht2[(size_t)pk * 64 + lane]);
        acc.x += fv.x;
        acc.y += fv.y;
    }

    unsigned short h0, l0, h1, l1;
    splitbf(acc.x, h0, l0);
    splitbf(acc.y, h1, l1);
    ((unsigned*)ahi)[(size_t)n * 64 + lane] = (unsigned)h0 | ((unsigned)h1 << 16);
    ((unsigned*)alo)[(size_t)n * 64 + lane] = (unsigned)l0 | ((unsigned)l1 << 16);
}

// ---------------------------------------------------------------------------
// Fused GRU, bf16x3 MFMA. Block = 512 thr = 8 waves, 64 rows x 128 cols.
// x-state staged in LDS once (all 8 waves read the same rows); weights from L2.
__global__ __launch_bounds__(512, 2) void gru_mfma(const ushort_t* __restrict__ ahi,
                                                   const ushort_t* __restrict__ alo,
                                                   ushort_t* __restrict__ hhi,
                                                   ushort_t* __restrict__ hlo,
                                                   const ushort_t* __restrict__ Wihi,
                                                   const ushort_t* __restrict__ Wilo,
                                                   const ushort_t* __restrict__ Whhi,
                                                   const ushort_t* __restrict__ Whlo,
                                                   const float* __restrict__ b_ih,
                                                   const float* __restrict__ b_hh,
                                                   float* __restrict__ h) {
    __shared__ __align__(16) ushort_t xlds[4][64 * TPAD];  // 69632 B
    const int tid = threadIdx.x;
    const int wave = tid >> 6, lane = tid & 63;
    const int q = lane >> 4, li = lane & 15;
    const int n0 = blockIdx.x * 64;
    const int f = wave * 16 + li;

    // ---- stage x-state: 4 arrays x 8192 ushorts; 512 thr x 2 x short8 each ----
#pragma unroll
    for (int i = 0; i < 2; ++i) {
        int g = (i * 512 + tid) * 8;   // 0..8184
        int row = g >> 7, col = g & 127;
        int gr = n0 + row;
        if (gr > N_NODES - 1) gr = N_NODES - 1;
        size_t go = (size_t)gr * D + col;
        int la = row * TPAD + col;
        *(short8*)(&xlds[0][la]) = *(const short8*)(ahi + go);
        *(short8*)(&xlds[1][la]) = *(const short8*)(alo + go);
        *(short8*)(&xlds[2][la]) = *(const short8*)(hhi + go);
        *(short8*)(&xlds[3][la]) = *(const short8*)(hlo + go);
    }
    __syncthreads();

    const size_t oR = (size_t)f * D + q * 8;
    const size_t oZ = (size_t)(D + f) * D + q * 8;
    const size_t oN = (size_t)(2 * D + f) * D + q * 8;

    float4v aR[4], aZ[4], aI[4], aH[4];
#pragma unroll
    for (int m = 0; m < 4; ++m) {
        aR[m] = (float4v){0.f, 0.f, 0.f, 0.f};
        aZ[m] = aR[m]; aI[m] = aR[m]; aH[m] = aR[m];
    }

#pragma unroll
    for (int ks = 0; ks < 4; ++ks) {
        const int off = ks * 32;
        short8 wIRh = *(const short8*)(Wihi + oR + off);
        short8 wIRl = *(const short8*)(Wilo + oR + off);
        short8 wHRh = *(const short8*)(Whhi + oR + off);
        short8 wHRl = *(const short8*)(Whlo + oR + off);
        short8 wIZh = *(const short8*)(Wihi + oZ + off);
        short8 wIZl = *(const short8*)(Wilo + oZ + off);
        short8 wHZh = *(const short8*)(Whhi + oZ + off);
        short8 wHZl = *(const short8*)(Whlo + oZ + off);
        short8 wINh = *(const short8*)(Wihi + oN + off);
        short8 wINl = *(const short8*)(Wilo + oN + off);
        short8 wHNh = *(const short8*)(Whhi + oN + off);
        short8 wHNl = *(const short8*)(Whlo + oN + off);
#pragma unroll
        for (int m = 0; m < 4; ++m) {
            const int lo_off = (m * 16 + li) * TPAD + off + q * 8;
            short8 xah = *(const short8*)(&xlds[0][lo_off]);
            short8 xal = *(const short8*)(&xlds[1][lo_off]);
            short8 xhh = *(const short8*)(&xlds[2][lo_off]);
            short8 xhl = *(const short8*)(&xlds[3][lo_off]);
            aR[m] = __builtin_amdgcn_mfma_f32_16x16x32_bf16(xah, wIRh, aR[m], 0, 0, 0);
            aR[m] = __builtin_amdgcn_mfma_f32_16x16x32_bf16(xal, wIRh, aR[m], 0, 0, 0);
            aR[m] = __builtin_amdgcn_mfma_f32_16x16x32_bf16(xah, wIRl, aR[m], 0, 0, 0);
            aR[m] = __builtin_amdgcn_mfma_f32_16x16x32_bf16(xhh, wHRh, aR[m], 0, 0, 0);
            aR[m] = __builtin_amdgcn_mfma_f32_16x16x32_bf16(xhl, wHRh, aR[m], 0, 0, 0);
            aR[m] = __builtin_amdgcn_mfma_f32_16x16x32_bf16(xhh, wHRl, aR[m], 0, 0, 0);
            aZ[m] = __builtin_amdgcn_mfma_f32_16x16x32_bf16(xah, wIZh, aZ[m], 0, 0, 0);
            aZ[m] = __builtin_amdgcn_mfma_f32_16x16x32_bf16(xal, wIZh, aZ[m], 0, 0, 0);
            aZ[m] = __builtin_amdgcn_mfma_f32_16x16x32_bf16(xah, wIZl, aZ[m], 0, 0, 0);
            aZ[m] = __builtin_amdgcn_mfma_f32_16x16x32_bf16(xhh, wHZh, aZ[m], 0, 0, 0);
            aZ[m] = __builtin_amdgcn_mfma_f32_16x16x32_bf16(xhl, wHZh, aZ[m], 0, 0, 0);
            aZ[m] = __builtin_amdgcn_mfma_f32_16x16x32_bf16(xhh, wHZl, aZ[m], 0, 0, 0);
            aI[m] = __builtin_amdgcn_mfma_f32_16x16x32_bf16(xah, wINh, aI[m], 0, 0, 0);
            aI[m] = __builtin_amdgcn_mfma_f32_16x16x32_bf16(xal, wINh, aI[m], 0, 0, 0);
            aI[m] = __builtin_amdgcn_mfma_f32_16x16x32_bf16(xah, wINl, aI[m], 0, 0, 0);
            aH[m] = __builtin_amdgcn_mfma_f32_16x16x32_bf16(xhh, wHNh, aH[m], 0, 0, 0);
            aH[m] = __builtin_amdgcn_mfma_f32_16x16x32_bf16(xhl, wHNh, aH[m], 0, 0, 0);
            aH[m] = __builtin_amdgcn_mfma_f32_16x16x32_bf16(xhh, wHNl, aH[m], 0, 0, 0);
        }
    }

    const float bR = b_ih[f] + b_hh[f];
    const float bZ = b_ih[D + f] + b_hh[D + f];
    const float bIn = b_ih[2 * D + f];
    const float bHn = b_hh[2 * D + f];

    // hold reads are (node,f)-exclusive to this lane; x reads came from LDS,
    // so no barrier needed before in-place writes (rows are block-exclusive).
#pragma unroll
    for (int m = 0; m < 4; ++m) {
#pragma unroll
        for (int r = 0; r < 4; ++r) {
            int node = n0 + m * 16 + q * 4 + r;
            if (node < N_NODES) {
                float hold = h[(size_t)node * D + f];
                float rg = 1.0f / (1.0f + __expf(-(aR[m][r] + bR)));
                float zg = 1.0f / (1.0f + __expf(-(aZ[m][r] + bZ)));
                float narg = aI[m][r] + bIn + rg * (aH[m][r] + bHn);
                float ex = __expf(2.0f * narg);
                float ng = 1.0f - 2.0f / (ex + 1.0f);   // tanh
                float hn = (1.0f - zg) * ng + zg * hold;
                h[(size_t)node * D + f] = hn;
                unsigned short sh, sl;
                splitbf(hn, sh, sl);
                hhi[(size_t)node * D + f] = sh;
                hlo[(size_t)node * D + f] = sl;
            }
        }
    }
}

// ---------------------------------------------------------------------------
extern "C" void kernel_launch(void* const* d_in, const int* in_sizes, int n_in,
                              void* d_out, int out_size, void* d_ws, size_t ws_size,
                              hipStream_t stream) {
    const int* x      = (const int*)d_in[0];
    const int* ei     = (const int*)d_in[1];
    const int* et     = (const int*)d_in[2];
    const int* nt     = (const int*)d_in[3];
    const float* emb  = (const float*)d_in[4];
    const float* Wrel = (const float*)d_in[5];
    const float* b_node = (const float*)d_in[6];
    const float* W_ih = (const float*)d_in[7];
    const float* W_hh = (const float*)d_in[8];
    const float* b_ih = (const float*)d_in[9];
    const float* b_hh = (const float*)d_in[10];

    float* h = (float*)d_out;
    float* ws = (float*)d_ws;

    // workspace layout (total ~158 MB, well under proven >=234 MB)
    ushort_t* Ht = (ushort_t*)ws;                          // 51,200,000 us (fp16)
    ushort_t* us = (ushort_t*)(ws + 25600000);
    ushort_t* ahi  = us;                                   // 6,400,000 each
    ushort_t* alo  = us + 6400000;
    ushort_t* hhi  = us + 12800000;
    ushort_t* hlo  = us + 19200000;
    ushort_t* Whi  = us + 25600000;                        //   131,072 each
    ushort_t* Wlo  = Whi + 131072;
    ushort_t* Wihi = Wlo + 131072;                         //    49,152 each
    ushort_t* Wilo = Wihi + 49152;
    ushort_t* Whhi = Wilo + 49152;
    ushort_t* Whlo = Whhi + 49152;
    int* rs     = (int*)(ws + 38629376);                   //    50,004
    int* packed = rs + 50004;                              //   800,000
    int* bsums  = packed + 800000;                         //       256
    int* deg    = (int*)ws;                                // transient alias in Ht region (pre-loop only)

    convert_wrelT<<<512, 256, 0, stream>>>(Wrel, Whi, Wlo);
    convert_w<<<192, 256, 0, stream>>>(W_ih, Wihi, Wilo, 3 * D * D);
    convert_w<<<192, 256, 0, stream>>>(W_hh, Whhi, Whlo, 3 * D * D);
    embed_gather<<<N_NODES, 128, 0, stream>>>(x, emb, h, hhi, hlo);

    hipMemsetAsync(deg, 0, 50000 * sizeof(int), stream);
    count_deg<<<3125, 256, 0, stream>>>(ei, deg);
    scan_blocks<<<NBLK_SCAN, 256, 0, stream>>>(deg, bsums);
    scan_tops<<<1, 256, 0, stream>>>(bsums);
    scan_final<<<NBLK_SCAN, 256, 0, stream>>>(bsums, deg, rs);   // cursor aliases deg
    fill_csr<<<3125, 256, 0, stream>>>(ei, et, deg, packed);

    for (int it = 0; it < 5; ++it) {
        dim3 g(391, T_TYPES);   // 391*128 = 50048 rows
        gemm_rel<<<g, 256, 0, stream>>>(hhi, hlo, Whi, Wlo, Ht);
        aggregate_csr<<<12500, 256, 0, stream>>>(rs, packed, Ht, nt, b_node, ahi, alo);
        gru_mfma<<<782, 512, 0, stream>>>(ahi, alo, hhi, hlo,
                                          Wihi, Wilo, Whhi, Whlo, b_ih, b_hh, h);
    }
}